// Round 11
// baseline (351.194 us; speedup 1.0000x reference)
//
#include <hip/hip_runtime.h>
#include <hip/hip_bf16.h>

typedef _Float16 half8 __attribute__((ext_vector_type(8)));
typedef _Float16 half4 __attribute__((ext_vector_type(4)));
typedef float f32x4 __attribute__((ext_vector_type(4)));

#define KDIM 1024
#define NDIM 1024
#define MROWS 16384   // B*L = 4*4096

#define GLD_LDS16(g, l)                                                  \
  __builtin_amdgcn_global_load_lds(                                      \
      (const __attribute__((address_space(1))) void*)(g),                \
      (__attribute__((address_space(3))) void*)(l), 16, 0, 0)

// ---------------------------------------------------------------------------
// fp32 -> fp16 convert (weights only), 32 elems/thread.
// ---------------------------------------------------------------------------
__global__ __launch_bounds__(256)
void cvt32(const float* __restrict__ s0, _Float16* __restrict__ d0,
           const float* __restrict__ s1, _Float16* __restrict__ d1,
           const float* __restrict__ s2, _Float16* __restrict__ d2,
           const float* __restrict__ s3, _Float16* __restrict__ d3) {
  const float* src;
  _Float16* dst;
  switch (blockIdx.y) {
    case 0: src = s0; dst = d0; break;
    case 1: src = s1; dst = d1; break;
    case 2: src = s2; dst = d2; break;
    default: src = s3; dst = d3; break;
  }
  const size_t g = (size_t)blockIdx.x * 8192;
  const int tid = threadIdx.x;
  float4 f[8];
#pragma unroll
  for (int j = 0; j < 8; ++j)
    f[j] = *(const float4*)(src + g + j * 1024 + tid * 4);
#pragma unroll
  for (int j = 0; j < 4; ++j) {
    half8 h;
    h[0] = (_Float16)f[2 * j].x;     h[1] = (_Float16)f[2 * j].y;
    h[2] = (_Float16)f[2 * j].z;     h[3] = (_Float16)f[2 * j].w;
    h[4] = (_Float16)f[2 * j + 1].x; h[5] = (_Float16)f[2 * j + 1].y;
    h[6] = (_Float16)f[2 * j + 1].z; h[7] = (_Float16)f[2 * j + 1].w;
    *(half4*)(dst + g + 2 * j * 1024 + tid * 4) = half4{h[0], h[1], h[2], h[3]};
    *(half4*)(dst + g + (2 * j + 1) * 1024 + tid * 4) = half4{h[4], h[5], h[6], h[7]};
  }
}

// ---------------------------------------------------------------------------
// BK32 GEMM: Y = act(X @ W^T + bias). 256x128, BK=32, 8 waves, 3-buf 72KB,
// 2 blocks/CU, counted-vmcnt 2-ahead B pipeline.
// SWIZZLE FIX (round-11): 64B LDS rows have only 2 bank phases, so the
// conflict-free XOR is slot ^= (row>>1)&3 (quad = 4*(row&1)+slot). Applied
// consistently to: ds_read slot (rsl), gld_lds inverse source (gsl), and
// the F32A ds_write slot. Round 7-10 used row&3 -> 4-way conflicts.
// TA=float: A read fp32 directly from d_in; ISSUE at iter top, convert+
//   ds_write AFTER the MFMA into buf (t+1)%3 (last read at t-2, safe);
//   the compiler's vmcnt wait before the writes also covers B(t+1);
//   trailing sync = lgkmcnt(0)+barrier only, B(t+2) stays in flight.
// TA=_Float16: A via global_load_lds (counted vmcnt(3)).
// FUSE: 1 = linear-attention epilogue (Ct overlays smem; KVTx B-frags from
// global, L2-hot). Requires ACT=1, TRANS=0, TOUT=_Float16.
// ---------------------------------------------------------------------------
template <int ACT, int TRANS, int FUSE, typename TA, typename TOUT>
__global__ __launch_bounds__(512, 2)
void gemm_bk32(const TA* __restrict__ X, const _Float16* __restrict__ W,
               const float* __restrict__ bias, TOUT* __restrict__ Y,
               const _Float16* __restrict__ KVTx) {
  constexpr int BM = 256, BN = 128, BK = 32;
  constexpr bool F32A = (sizeof(TA) == 4);
  __shared__ char smem[73728];                    // 72 KB
  _Float16* As = (_Float16*)smem;                 // 48 KB (3 x 16 KB)
  _Float16* Bs = (_Float16*)(smem + 49152);       // 24 KB (3 x 8 KB)

  const int tid  = threadIdx.x;
  const int lane = tid & 63;
  const int w    = tid >> 6;
  const int wm   = w >> 1;
  const int wn   = w & 1;

  const int bid = blockIdx.x;
  const int wid = (bid & 7) * 64 + (bid >> 3);
  const int m0  = (wid >> 3) * BM;
  const int n0  = (wid & 7) * BN;

  // ---- B staging (always gld_lds, fp16 weights); lane -> row lane>>2,
  // LDS slot lane&3; source slot = (lane&3) ^ f(row), f(row)=(row>>1)&3
  const int lrw = lane >> 2;                       // 0..15
  const int gsl = (lane & 3) ^ ((lane >> 3) & 3);  // inverse-swizzled slot
  const _Float16* gB = W + (size_t)(n0 + w * 16 + lrw) * KDIM + gsl * 8;
#define GLDB(kt, bidx)                                                        \
  GLD_LDS16(gB + (kt) * BK, Bs + (bidx) * (BN * BK) + (w * 16) * BK)

  // ---- A staging, fp16 path (gld_lds)
  const _Float16* gA16 =
      (const _Float16*)X + (size_t)(m0 + w * 16 + lrw) * KDIM + gsl * 8;
#define GLDA16(kt, bidx)                                                      \
  {                                                                           \
    _Float16* la = As + (bidx) * (BM * BK) + (w * 16) * BK;                   \
    GLD_LDS16(gA16 + (kt) * BK, la);                                          \
    GLD_LDS16(gA16 + (size_t)128 * KDIM + (kt) * BK, la + 128 * BK);          \
  }
  // ---- A staging, fp32 path (reg-stage + cvt + swizzled ds_write)
  const int sr2  = tid >> 1;
  const int kh   = tid & 1;
  const int wswz = (sr2 >> 1) & 3;
  const float* gA32 = (const float*)X + (size_t)(m0 + sr2) * KDIM + kh * 16;
  float4 ar[4];
#define ISSUEA32(kt)                                                          \
  {                                                                           \
    _Pragma("unroll")                                                         \
    for (int j = 0; j < 4; ++j)                                               \
      ar[j] = *(const float4*)(gA32 + (kt) * BK + j * 4);                     \
  }
#define CVTWRA32(bidx)                                                        \
  {                                                                           \
    _Pragma("unroll")                                                         \
    for (int j = 0; j < 2; ++j) {                                             \
      half8 h;                                                                \
      h[0] = (_Float16)ar[2 * j].x;     h[1] = (_Float16)ar[2 * j].y;         \
      h[2] = (_Float16)ar[2 * j].z;     h[3] = (_Float16)ar[2 * j].w;         \
      h[4] = (_Float16)ar[2 * j + 1].x; h[5] = (_Float16)ar[2 * j + 1].y;     \
      h[6] = (_Float16)ar[2 * j + 1].z; h[7] = (_Float16)ar[2 * j + 1].w;     \
      int slot = (2 * kh + j) ^ wswz;                                         \
      *(half8*)((char*)As + (bidx) * 16384 + sr2 * 64 + slot * 16) = h;       \
    }                                                                         \
  }

  // read swizzle: row = base + (lane&15); f(row) = (lane>>1)&3
  const int rsl = ((lane >> 4) ^ ((lane >> 1) & 3)) << 4;

  f32x4 acc[4][4] = {};

  // ---- prologue
  if constexpr (F32A) {
    ISSUEA32(0);
    GLDB(0, 0);
    GLDB(1, 1);
    CVTWRA32(0);                 // implicit vmcnt waits A0 (B0,B1 newer)
    asm volatile("s_waitcnt vmcnt(1) lgkmcnt(0)" ::: "memory");  // B0 landed
    asm volatile("s_barrier" ::: "memory");
  } else {
    GLDA16(0, 0); GLDB(0, 0);
    GLDA16(1, 1); GLDB(1, 1);
    asm volatile("s_waitcnt vmcnt(3)" ::: "memory");
    asm volatile("s_barrier" ::: "memory");
  }

  int bc = 0;
  for (int t = 0; t < 32; ++t) {
    int b1 = bc + 1; if (b1 == 3) b1 = 0;
    int bs = bc + 2; if (bs >= 3) bs -= 3;
    const char* Ab = (const char*)As + bc * (BM * BK * 2);
    const char* Bb = (const char*)Bs + bc * (BN * BK * 2);

    // issue A(t+1) early: consumed after MFMA (flight ~ full compute phase)
    if constexpr (F32A) {
      if (t < 31) ISSUEA32(t + 1);
    }

    half8 afr[4], bfr[4];
#pragma unroll
    for (int mi = 0; mi < 4; ++mi) {
      int row = wm * 64 + mi * 16 + (lane & 15);
      afr[mi] = *(const half8*)(Ab + row * 64 + rsl);
    }
#pragma unroll
    for (int ni = 0; ni < 4; ++ni) {
      int row = wn * 64 + ni * 16 + (lane & 15);
      bfr[ni] = *(const half8*)(Bb + row * 64 + rsl);
    }

    if constexpr (F32A) {
      if (t < 30) GLDB(t + 2, bs);
    } else {
      if (t < 30) { GLDA16(t + 2, bs); GLDB(t + 2, bs); }
    }

    __builtin_amdgcn_s_setprio(1);
#pragma unroll
    for (int mi = 0; mi < 4; ++mi)
#pragma unroll
      for (int ni = 0; ni < 4; ++ni)
        acc[mi][ni] = __builtin_amdgcn_mfma_f32_16x16x32_f16(
            afr[mi], bfr[ni], acc[mi][ni], 0, 0, 0);
    __builtin_amdgcn_s_setprio(0);

    if constexpr (F32A) {
      if (t < 31) {
        CVTWRA32(b1);   // implicit vmcnt(1): A(t+1) done => B(t+1) done too
        asm volatile("s_waitcnt lgkmcnt(0)" ::: "memory");  // writes visible
        asm volatile("s_barrier" ::: "memory");             // B(t+2) in flight
      }
    } else {
      if (t < 30) {
        asm volatile("s_waitcnt vmcnt(3)" ::: "memory");
        asm volatile("s_barrier" ::: "memory");
      } else if (t == 30) {
        asm volatile("s_waitcnt vmcnt(0)" ::: "memory");
        asm volatile("s_barrier" ::: "memory");
      }
    }
    ++bc; if (bc == 3) bc = 0;
  }
#undef GLDB
#undef GLDA16
#undef ISSUEA32
#undef CVTWRA32

  if constexpr (FUSE) {
    // ---- fused linear-attention epilogue (Ct overlays smem; B from global)
    __syncthreads();
    _Float16* Ct = (_Float16*)smem;   // [256 rows][128 cols], 256B rows
#pragma unroll
    for (int ni = 0; ni < 4; ++ni) {
      int cl   = wn * 64 + ni * 16 + (lane & 15);
      float bv = bias[n0 + cl];
#pragma unroll
      for (int mi = 0; mi < 4; ++mi) {
#pragma unroll
        for (int i = 0; i < 4; ++i) {
          int row = wm * 64 + mi * 16 + ((lane >> 4) << 2) + i;
          float v = acc[mi][ni][i] + bv;
          v = (v > 0.f) ? (v + 1.f) : __expf(v);
          int byte = row * 256 + cl * 2;
          byte ^= (row & 7) << 4;
          *(_Float16*)((char*)Ct + byte) = (_Float16)v;
        }
      }
    }
    __syncthreads();
    const int bh0 = ((m0 >> 12) << 4) + (n0 >> 6);
    const _Float16* kvp = KVTx + (size_t)(bh0 + wn) * 5120;
    f32x4 acc2[4][5] = {};
#pragma unroll
    for (int kk = 0; kk < 2; ++kk) {
      half8 afr2[4], bfr2[5];
#pragma unroll
      for (int m = 0; m < 4; ++m) {
        int row  = wm * 64 + m * 16 + (lane & 15);
        int byte = row * 256 + wn * 128 + kk * 64 + ((lane >> 4) << 4);
        byte ^= (row & 7) << 4;
        afr2[m] = *(const half8*)((const char*)Ct + byte);
      }
#pragma unroll
      for (int n = 0; n < 5; ++n) {
        int row = n * 16 + (lane & 15);
        bfr2[n] = *(const half8*)(kvp + row * 64 + kk * 32 + ((lane >> 4) << 3));
      }
#pragma unroll
      for (int m = 0; m < 4; ++m)
#pragma unroll
        for (int n = 0; n < 5; ++n)
          acc2[m][n] = __builtin_amdgcn_mfma_f32_16x16x32_f16(
              afr2[m], bfr2[n], acc2[m][n], 0, 0, 0);
    }
#pragma unroll
    for (int m = 0; m < 4; ++m) {
#pragma unroll
      for (int i = 0; i < 4; ++i) {
        float dn = __shfl(acc2[m][4][i], lane & 48);
        float z  = 1.f / (dn + 1e-6f);
        size_t row = (size_t)m0 + wm * 64 + m * 16 + ((lane >> 4) << 2) + i;
#pragma unroll
        for (int n = 0; n < 4; ++n) {
          int col = n0 + wn * 64 + n * 16 + (lane & 15);
          Y[row * NDIM + col] = (TOUT)(acc2[m][n][i] * z);
        }
      }
    }
    return;
  }

#pragma unroll
  for (int ni = 0; ni < 4; ++ni) {
    int col  = n0 + wn * 64 + ni * 16 + (lane & 15);
    float bv = bias[col];
#pragma unroll
    for (int mi = 0; mi < 4; ++mi) {
      int r0 = m0 + wm * 64 + mi * 16 + ((lane >> 4) << 2);
      if constexpr (TRANS) {
        int b  = r0 >> 12;
        int l0 = r0 & 4095;
        half4 hv;
#pragma unroll
        for (int i = 0; i < 4; ++i) {
          float v = acc[mi][ni][i] + bv;
          if constexpr (ACT == 1) v = (v > 0.f) ? (v + 1.f) : __expf(v);
          hv[i] = (_Float16)v;
        }
        *(half4*)((_Float16*)Y + ((size_t)(b * 1024 + col)) * 4096 + l0) = hv;
      } else {
#pragma unroll
        for (int i = 0; i < 4; ++i) {
          float v = acc[mi][ni][i] + bv;
          if constexpr (ACT == 1) v = (v > 0.f) ? (v + 1.f) : __expf(v);
          Y[(size_t)(r0 + i) * NDIM + col] = (TOUT)v;
        }
      }
    }
  }
}

// ---------------------------------------------------------------------------
// kv_mfma: per (bh, chunk of 1024 l): partial C'[e][d] = sum_l VT[e][l]*KT[d][l]
// A = VT rows + synthesized ones-row (m-frag 4 -> Ksum); B = KT rows.
// ---------------------------------------------------------------------------
__global__ __launch_bounds__(256, 2)
void kv_mfma(const _Float16* __restrict__ KT, const _Float16* __restrict__ VT,
             _Float16* __restrict__ pKV) {
  const int bh = blockIdx.x;      // 0..63
  const int ch = blockIdx.y;      // 0..3
  const int tid  = threadIdx.x;
  const int lane = tid & 63;
  const int w    = tid >> 6;

  __shared__ _Float16 As[64 * 64];
  __shared__ _Float16 Bs[64 * 64];

  const int lr = lane >> 3;
  const int ls = (lane & 7) ^ lr;
  const size_t lbase = (size_t)ch * 1024 + ls * 8;
  const _Float16* gA = VT + (size_t)(bh * 64 + w * 16 + lr) * 4096 + lbase;
  const _Float16* gB = KT + (size_t)(bh * 64 + w * 16 + lr) * 4096 + lbase;
  _Float16* ldsA = As + (w * 16) * 64;
  _Float16* ldsB = Bs + (w * 16) * 64;

  half8 aones;
#pragma unroll
  for (int j = 0; j < 8; ++j) aones[j] = (lane & 15) == 0 ? (_Float16)1.0f : (_Float16)0.0f;

  f32x4 acc[5] = {};

  for (int k0 = 0; k0 < 1024; k0 += 64) {
    __syncthreads();
#pragma unroll
    for (int c = 0; c < 2; ++c) {
      GLD_LDS16(gA + k0 + (size_t)(c * 8) * 4096, ldsA + c * 8 * 64);
      GLD_LDS16(gB + k0 + (size_t)(c * 8) * 4096, ldsB + c * 8 * 64);
    }
    __syncthreads();

    half8 afr[4][2], bfr[2];
#pragma unroll
    for (int m = 0; m < 4; ++m)
#pragma unroll
      for (int kk = 0; kk < 2; ++kk) {
        int row  = m * 16 + (lane & 15);
        int byte = row * 128 + ((lane >> 4) << 4) + kk * 64;
        byte ^= (row & 7) << 4;
        afr[m][kk] = *(const half8*)((const char*)As + byte);
      }
#pragma unroll
    for (int kk = 0; kk < 2; ++kk) {
      int row  = w * 16 + (lane & 15);
      int byte = row * 128 + ((lane >> 4) << 4) + kk * 64;
      byte ^= (row & 7) << 4;
      bfr[kk] = *(const half8*)((const char*)Bs + byte);
    }
#pragma unroll
    for (int kk = 0; kk < 2; ++kk) {
#pragma unroll
      for (int m = 0; m < 4; ++m)
        acc[m] = __builtin_amdgcn_mfma_f32_16x16x32_f16(afr[m][kk], bfr[kk],
                                                        acc[m], 0, 0, 0);
      acc[4] = __builtin_amdgcn_mfma_f32_16x16x32_f16(aones, bfr[kk],
                                                      acc[4], 0, 0, 0);
    }
  }

  _Float16* outp = pKV + ((size_t)ch * 64 + bh) * 5120;
  const int col = w * 16 + (lane & 15);
#pragma unroll
  for (int m = 0; m < 5; ++m) {
#pragma unroll
    for (int i = 0; i < 4; ++i) {
      int row = m * 16 + ((lane >> 4) << 2) + i;
      outp[row * 64 + col] = (_Float16)acc[m][i];
    }
  }
}

// ---------------------------------------------------------------------------
// Combine 4 fp16 partials -> KVTx fp16 [64 bh][80 rows][64 cols]
// ---------------------------------------------------------------------------
__global__ __launch_bounds__(256)
void kv_combine(const _Float16* __restrict__ pKV, _Float16* __restrict__ KVTx) {
  int g = blockIdx.x * 256 + threadIdx.x;   // 0..327679
  int bh = g / 5120;
  int j  = g - bh * 5120;
  float s = 0.f;
#pragma unroll
  for (int ch = 0; ch < 4; ++ch)
    s += (float)pKV[((size_t)ch * 64 + bh) * 5120 + j];
  KVTx[(size_t)bh * 5120 + j] = (_Float16)s;
}

// ---------------------------------------------------------------------------
extern "C" void kernel_launch(void* const* d_in, const int* in_sizes, int n_in,
                              void* d_out, int out_size, void* d_ws, size_t ws_size,
                              hipStream_t stream) {
  const float* q  = (const float*)d_in[0];
  const float* k  = (const float*)d_in[1];
  const float* v  = (const float*)d_in[2];
  const float* wq = (const float*)d_in[3];
  const float* bq = (const float*)d_in[4];
  const float* wk = (const float*)d_in[5];
  const float* bk = (const float*)d_in[6];
  const float* wv = (const float*)d_in[7];
  const float* bv = (const float*)d_in[8];
  const float* wo = (const float*)d_in[9];
  const float* bo = (const float*)d_in[10];
  float* out = (float*)d_out;

  char* ws = (char*)d_ws;
  _Float16* pKV  = (_Float16*)(ws);                      // 2.62MB (kv stage)
  _Float16* KVTx = (_Float16*)(ws + 4194304);            // 640KB
  _Float16* KT   = (_Float16*)(ws + 33554432);           // 32..64MB
  _Float16* VT   = (_Float16*)(ws + 67108864);           // 64..96MB
  _Float16* whk  = (_Float16*)(ws + 100663296);          // 2MB
  _Float16* whv  = (_Float16*)(ws + 102760448);          // 2MB
  _Float16* whq  = (_Float16*)(ws + 104857600);          // 2MB
  _Float16* who  = (_Float16*)(ws + 106954752);          // 2MB
  _Float16* att  = KT;                                   // reuse KT after KV built

  const int GBLK = (MROWS / 256) * (NDIM / 128);   // 512 blocks

  // weights only (1M elems each -> 128 blocks x 8192)
  cvt32<<<dim3(128, 4), 256, 0, stream>>>(wq, whq, wk, whk, wv, whv, wo, who);

  // K/V projections: fp32 A read directly from d_in (no input cvt pass)
  gemm_bk32<1, 1, 0, float, _Float16><<<GBLK, 512, 0, stream>>>(k, whk, bk, KT, nullptr);
  gemm_bk32<0, 1, 0, float, _Float16><<<GBLK, 512, 0, stream>>>(v, whv, bv, VT, nullptr);

  kv_mfma<<<dim3(64, 4), 256, 0, stream>>>(KT, VT, pKV);
  kv_combine<<<1280, 256, 0, stream>>>(pKV, KVTx);

  // Q projection + attention fused (fp32 A direct + global-B-frag epilogue)
  gemm_bk32<1, 0, 1, float, _Float16><<<GBLK, 512, 0, stream>>>(q, whq, bq, att, KVTx);

  // output projection (fp16 A = att, gld_lds path); writes d_out
  gemm_bk32<0, 0, 0, _Float16, float><<<GBLK, 512, 0, stream>>>(att, who, bo, out, nullptr);
}

// Round 12
// 262.770 us; speedup vs baseline: 1.3365x; 1.3365x over previous
//
#include <hip/hip_runtime.h>
#include <hip/hip_bf16.h>

typedef _Float16 half8 __attribute__((ext_vector_type(8)));
typedef _Float16 half4 __attribute__((ext_vector_type(4)));
typedef float f32x4 __attribute__((ext_vector_type(4)));

#define KDIM 1024
#define NDIM 1024
#define MROWS 16384   // B*L = 4*4096

#define GLD_LDS16(g, l)                                                  \
  __builtin_amdgcn_global_load_lds(                                      \
      (const __attribute__((address_space(1))) void*)(g),                \
      (__attribute__((address_space(3))) void*)(l), 16, 0, 0)

// ---------------------------------------------------------------------------
// Max-TLP fp32->fp16 convert: ONE float4 load + ONE half4 store per thread,
// no loop, exact grid. (Round-9's 8-loads/thread version had VGPR_Count=20
// < 32 needed -> compiler serialized the load chain -> 3.8 TB/s. TLP-pure
// shape instead relies on 2048 threads/CU for MLP.)
// ---------------------------------------------------------------------------
__global__ __launch_bounds__(256)
void cvt_in(const float* __restrict__ s0, _Float16* __restrict__ d0,
            const float* __restrict__ s1, _Float16* __restrict__ d1,
            const float* __restrict__ s2, _Float16* __restrict__ d2) {
  const float* src;
  _Float16* dst;
  switch (blockIdx.y) {
    case 0: src = s0; dst = d0; break;
    case 1: src = s1; dst = d1; break;
    default: src = s2; dst = d2; break;
  }
  size_t i = (size_t)blockIdx.x * 256 + threadIdx.x;   // float4 index
  float4 f = ((const float4*)src)[i];
  half4 h;
  h[0] = (_Float16)f.x; h[1] = (_Float16)f.y;
  h[2] = (_Float16)f.z; h[3] = (_Float16)f.w;
  ((half4*)dst)[i] = h;
}

__global__ __launch_bounds__(256)
void cvt_w(const float* __restrict__ s0, _Float16* __restrict__ d0,
           const float* __restrict__ s1, _Float16* __restrict__ d1,
           const float* __restrict__ s2, _Float16* __restrict__ d2,
           const float* __restrict__ s3, _Float16* __restrict__ d3) {
  const float* src;
  _Float16* dst;
  switch (blockIdx.y) {
    case 0: src = s0; dst = d0; break;
    case 1: src = s1; dst = d1; break;
    case 2: src = s2; dst = d2; break;
    default: src = s3; dst = d3; break;
  }
  size_t i = (size_t)blockIdx.x * 256 + threadIdx.x;
  float4 f = ((const float4*)src)[i];
  half4 h;
  h[0] = (_Float16)f.x; h[1] = (_Float16)f.y;
  h[2] = (_Float16)f.z; h[3] = (_Float16)f.w;
  ((half4*)dst)[i] = h;
}

// ---------------------------------------------------------------------------
// BK32 GEMM (round-8 proven, reverted verbatim): Y = act(X @ W^T + bias),
// fp16 in, fp32 accum. 256x128, BK=32, 8 waves, 3-buf 72KB unified smem ->
// 2 blocks/CU. Counted-vmcnt(3) 2-ahead pipeline, rule-21 swizzle
// (slot ^= row&3 via inverse-swizzled global source).
// ACT: 0 none, 1 elu+1. TRANS: 1 = per-head transposed fp16 (half4).
// FUSE: 1 = linear-attention epilogue: Ct (64KB, overlays smem) re-fragments
// Q as MFMA-A; KVTx B-fragments read DIRECTLY from global (L2-hot);
// Z-scale; store att fp16 natural. Requires ACT=1, TRANS=0, TOUT=_Float16.
// ---------------------------------------------------------------------------
template <int ACT, int TRANS, int FUSE, typename TOUT>
__global__ __launch_bounds__(512, 2)
void gemm_bk32(const _Float16* __restrict__ X, const _Float16* __restrict__ W,
               const float* __restrict__ bias, TOUT* __restrict__ Y,
               const _Float16* __restrict__ KVTx) {
  constexpr int BM = 256, BN = 128, BK = 32;
  __shared__ char smem[73728];                    // 72 KB
  _Float16* As = (_Float16*)smem;                 // 48 KB (3 x 16 KB)
  _Float16* Bs = (_Float16*)(smem + 49152);       // 24 KB (3 x 8 KB)

  const int tid  = threadIdx.x;
  const int lane = tid & 63;
  const int w    = tid >> 6;
  const int wm   = w >> 1;
  const int wn   = w & 1;

  const int bid = blockIdx.x;
  const int wid = (bid & 7) * 64 + (bid >> 3);
  const int m0  = (wid >> 3) * BM;
  const int n0  = (wid & 7) * BN;

  const int lrw = lane >> 2;                     // 0..15
  const int gsl = (lane & 3) ^ (lrw & 3);        // inverse-swizzled slot
  const _Float16* gA = X + (size_t)(m0 + w * 16 + lrw) * KDIM + gsl * 8;
  const _Float16* gB = W + (size_t)(n0 + w * 16 + lrw) * KDIM + gsl * 8;

#define STAGE32(kt, bidx)                                                     \
  {                                                                           \
    const int k0s = (kt) * BK;                                                \
    _Float16* la = As + (bidx) * (BM * BK) + (w * 16) * BK;                   \
    _Float16* lb = Bs + (bidx) * (BN * BK) + (w * 16) * BK;                   \
    GLD_LDS16(gA + k0s, la);                                                  \
    GLD_LDS16(gA + (size_t)128 * KDIM + k0s, la + 128 * BK);                  \
    GLD_LDS16(gB + k0s, lb);                                                  \
  }

  const int rsl = ((lane >> 4) ^ (lane & 3)) << 4;

  f32x4 acc[4][4] = {};

  STAGE32(0, 0);
  STAGE32(1, 1);
  asm volatile("s_waitcnt vmcnt(3)" ::: "memory");
  asm volatile("s_barrier" ::: "memory");

  int bc = 0;
  for (int t = 0; t < 32; ++t) {
    int bs = bc + 2; if (bs >= 3) bs -= 3;
    const char* Ab = (const char*)As + bc * (BM * BK * 2);
    const char* Bb = (const char*)Bs + bc * (BN * BK * 2);

    half8 afr[4], bfr[4];
#pragma unroll
    for (int mi = 0; mi < 4; ++mi) {
      int row = wm * 64 + mi * 16 + (lane & 15);
      afr[mi] = *(const half8*)(Ab + row * 64 + rsl);
    }
#pragma unroll
    for (int ni = 0; ni < 4; ++ni) {
      int row = wn * 64 + ni * 16 + (lane & 15);
      bfr[ni] = *(const half8*)(Bb + row * 64 + rsl);
    }

    if (t < 30) STAGE32(t + 2, bs);

    __builtin_amdgcn_s_setprio(1);
#pragma unroll
    for (int mi = 0; mi < 4; ++mi)
#pragma unroll
      for (int ni = 0; ni < 4; ++ni)
        acc[mi][ni] = __builtin_amdgcn_mfma_f32_16x16x32_f16(
            afr[mi], bfr[ni], acc[mi][ni], 0, 0, 0);
    __builtin_amdgcn_s_setprio(0);

    if (t < 30) {
      asm volatile("s_waitcnt vmcnt(3)" ::: "memory");
      asm volatile("s_barrier" ::: "memory");
    } else if (t == 30) {
      asm volatile("s_waitcnt vmcnt(0)" ::: "memory");
      asm volatile("s_barrier" ::: "memory");
    }
    ++bc; if (bc == 3) bc = 0;
  }
#undef STAGE32

  if constexpr (FUSE) {
    // ---- fused linear-attention epilogue (Ct overlays smem; B from global)
    __syncthreads();
    _Float16* Ct = (_Float16*)smem;   // [256 rows][128 cols], 256B rows
#pragma unroll
    for (int ni = 0; ni < 4; ++ni) {
      int cl   = wn * 64 + ni * 16 + (lane & 15);
      float bv = bias[n0 + cl];
#pragma unroll
      for (int mi = 0; mi < 4; ++mi) {
#pragma unroll
        for (int i = 0; i < 4; ++i) {
          int row = wm * 64 + mi * 16 + ((lane >> 4) << 2) + i;
          float v = acc[mi][ni][i] + bv;
          v = (v > 0.f) ? (v + 1.f) : __expf(v);
          int byte = row * 256 + cl * 2;
          byte ^= (row & 7) << 4;
          *(_Float16*)((char*)Ct + byte) = (_Float16)v;
        }
      }
    }
    __syncthreads();
    // B-fragments straight from KVTx (L2-hot): head = bh0 + wn
    const int bh0 = ((m0 >> 12) << 4) + (n0 >> 6);
    const _Float16* kvp = KVTx + (size_t)(bh0 + wn) * 5120;
    f32x4 acc2[4][5] = {};
#pragma unroll
    for (int kk = 0; kk < 2; ++kk) {
      half8 afr2[4], bfr2[5];
#pragma unroll
      for (int m = 0; m < 4; ++m) {
        int row  = wm * 64 + m * 16 + (lane & 15);
        int byte = row * 256 + wn * 128 + kk * 64 + ((lane >> 4) << 4);
        byte ^= (row & 7) << 4;
        afr2[m] = *(const half8*)((const char*)Ct + byte);
      }
#pragma unroll
      for (int n = 0; n < 5; ++n) {
        int row = n * 16 + (lane & 15);
        bfr2[n] = *(const half8*)(kvp + row * 64 + kk * 32 + ((lane >> 4) << 3));
      }
#pragma unroll
      for (int m = 0; m < 4; ++m)
#pragma unroll
        for (int n = 0; n < 5; ++n)
          acc2[m][n] = __builtin_amdgcn_mfma_f32_16x16x32_f16(
              afr2[m], bfr2[n], acc2[m][n], 0, 0, 0);
    }
#pragma unroll
    for (int m = 0; m < 4; ++m) {
#pragma unroll
      for (int i = 0; i < 4; ++i) {
        float dn = __shfl(acc2[m][4][i], lane & 48);
        float z  = 1.f / (dn + 1e-6f);
        size_t row = (size_t)m0 + wm * 64 + m * 16 + ((lane >> 4) << 2) + i;
#pragma unroll
        for (int n = 0; n < 4; ++n) {
          int col = n0 + wn * 64 + n * 16 + (lane & 15);
          Y[row * NDIM + col] = (TOUT)(acc2[m][n][i] * z);
        }
      }
    }
    return;
  }

#pragma unroll
  for (int ni = 0; ni < 4; ++ni) {
    int col  = n0 + wn * 64 + ni * 16 + (lane & 15);
    float bv = bias[col];
#pragma unroll
    for (int mi = 0; mi < 4; ++mi) {
      int r0 = m0 + wm * 64 + mi * 16 + ((lane >> 4) << 2);
      if constexpr (TRANS) {
        int b  = r0 >> 12;
        int l0 = r0 & 4095;
        half4 hv;
#pragma unroll
        for (int i = 0; i < 4; ++i) {
          float v = acc[mi][ni][i] + bv;
          if constexpr (ACT == 1) v = (v > 0.f) ? (v + 1.f) : __expf(v);
          hv[i] = (_Float16)v;
        }
        *(half4*)((_Float16*)Y + ((size_t)(b * 1024 + col)) * 4096 + l0) = hv;
      } else {
#pragma unroll
        for (int i = 0; i < 4; ++i) {
          float v = acc[mi][ni][i] + bv;
          if constexpr (ACT == 1) v = (v > 0.f) ? (v + 1.f) : __expf(v);
          Y[(size_t)(r0 + i) * NDIM + col] = (TOUT)v;
        }
      }
    }
  }
}

// ---------------------------------------------------------------------------
// kv_mfma: per (bh, chunk of 1024 l): partial C'[e][d] = sum_l VT[e][l]*KT[d][l]
// A = VT rows + synthesized ones-row (m-frag 4 -> Ksum); B = KT rows.
// ---------------------------------------------------------------------------
__global__ __launch_bounds__(256, 2)
void kv_mfma(const _Float16* __restrict__ KT, const _Float16* __restrict__ VT,
             _Float16* __restrict__ pKV) {
  const int bh = blockIdx.x;      // 0..63
  const int ch = blockIdx.y;      // 0..3
  const int tid  = threadIdx.x;
  const int lane = tid & 63;
  const int w    = tid >> 6;

  __shared__ _Float16 As[64 * 64];
  __shared__ _Float16 Bs[64 * 64];

  const int lr = lane >> 3;
  const int ls = (lane & 7) ^ lr;
  const size_t lbase = (size_t)ch * 1024 + ls * 8;
  const _Float16* gA = VT + (size_t)(bh * 64 + w * 16 + lr) * 4096 + lbase;
  const _Float16* gB = KT + (size_t)(bh * 64 + w * 16 + lr) * 4096 + lbase;
  _Float16* ldsA = As + (w * 16) * 64;
  _Float16* ldsB = Bs + (w * 16) * 64;

  half8 aones;
#pragma unroll
  for (int j = 0; j < 8; ++j) aones[j] = (lane & 15) == 0 ? (_Float16)1.0f : (_Float16)0.0f;

  f32x4 acc[5] = {};

  for (int k0 = 0; k0 < 1024; k0 += 64) {
    __syncthreads();
#pragma unroll
    for (int c = 0; c < 2; ++c) {
      GLD_LDS16(gA + k0 + (size_t)(c * 8) * 4096, ldsA + c * 8 * 64);
      GLD_LDS16(gB + k0 + (size_t)(c * 8) * 4096, ldsB + c * 8 * 64);
    }
    __syncthreads();

    half8 afr[4][2], bfr[2];
#pragma unroll
    for (int m = 0; m < 4; ++m)
#pragma unroll
      for (int kk = 0; kk < 2; ++kk) {
        int row  = m * 16 + (lane & 15);
        int byte = row * 128 + ((lane >> 4) << 4) + kk * 64;
        byte ^= (row & 7) << 4;
        afr[m][kk] = *(const half8*)((const char*)As + byte);
      }
#pragma unroll
    for (int kk = 0; kk < 2; ++kk) {
      int row  = w * 16 + (lane & 15);
      int byte = row * 128 + ((lane >> 4) << 4) + kk * 64;
      byte ^= (row & 7) << 4;
      bfr[kk] = *(const half8*)((const char*)Bs + byte);
    }
#pragma unroll
    for (int kk = 0; kk < 2; ++kk) {
#pragma unroll
      for (int m = 0; m < 4; ++m)
        acc[m] = __builtin_amdgcn_mfma_f32_16x16x32_f16(afr[m][kk], bfr[kk],
                                                        acc[m], 0, 0, 0);
      acc[4] = __builtin_amdgcn_mfma_f32_16x16x32_f16(aones, bfr[kk],
                                                      acc[4], 0, 0, 0);
    }
  }

  _Float16* outp = pKV + ((size_t)ch * 64 + bh) * 5120;
  const int col = w * 16 + (lane & 15);
#pragma unroll
  for (int m = 0; m < 5; ++m) {
#pragma unroll
    for (int i = 0; i < 4; ++i) {
      int row = m * 16 + ((lane >> 4) << 2) + i;
      outp[row * 64 + col] = (_Float16)acc[m][i];
    }
  }
}

// ---------------------------------------------------------------------------
// Combine 4 fp16 partials -> KVTx fp16 [64 bh][80 rows][64 cols]
// ---------------------------------------------------------------------------
__global__ __launch_bounds__(256)
void kv_combine(const _Float16* __restrict__ pKV, _Float16* __restrict__ KVTx) {
  int g = blockIdx.x * 256 + threadIdx.x;   // 0..327679
  int bh = g / 5120;
  int j  = g - bh * 5120;
  float s = 0.f;
#pragma unroll
  for (int ch = 0; ch < 4; ++ch)
    s += (float)pKV[((size_t)ch * 64 + bh) * 5120 + j];
  KVTx[(size_t)bh * 5120 + j] = (_Float16)s;
}

// ---------------------------------------------------------------------------
extern "C" void kernel_launch(void* const* d_in, const int* in_sizes, int n_in,
                              void* d_out, int out_size, void* d_ws, size_t ws_size,
                              hipStream_t stream) {
  const float* q  = (const float*)d_in[0];
  const float* k  = (const float*)d_in[1];
  const float* v  = (const float*)d_in[2];
  const float* wq = (const float*)d_in[3];
  const float* bq = (const float*)d_in[4];
  const float* wk = (const float*)d_in[5];
  const float* bk = (const float*)d_in[6];
  const float* wv = (const float*)d_in[7];
  const float* bv = (const float*)d_in[8];
  const float* wo = (const float*)d_in[9];
  const float* bo = (const float*)d_in[10];
  float* out = (float*)d_out;

  char* ws = (char*)d_ws;
  _Float16* Xq   = (_Float16*)(ws);                      // 0..32MB
  _Float16* KT   = (_Float16*)(ws + 33554432);           // 32..64MB
  _Float16* VT   = (_Float16*)(ws + 67108864);           // 64..96MB
  _Float16* pKV  = (_Float16*)(ws + 100663296);          // 2.62MB (over whk/whv later)
  _Float16* whk  = (_Float16*)(ws + 100663296);          // 2MB (dies after K-gemm)
  _Float16* whv  = (_Float16*)(ws + 102760448);          // 2MB (dies after V-gemm)
  _Float16* whq  = (_Float16*)(ws + 104857600);          // 2MB
  _Float16* who  = (_Float16*)(ws + 106954752);          // 2MB (lives to the end)
  _Float16* att  = KT;                                   // reuse KT after KV built
  // d_out (64MB) as scratch until the final GEMM:
  _Float16* Xk   = (_Float16*)d_out;                     // 0..32MB of d_out
  _Float16* Xv   = (_Float16*)((char*)d_out + 33554432); // 32..64MB of d_out
  _Float16* KVTx = (_Float16*)((char*)d_out + 33554432); // over dead Xv

  const int GBLK = (MROWS / 256) * (NDIM / 128);   // 512 blocks

  // converts: TLP-pure, 1 float4/thread. inputs: 4,194,304 f4 -> (16384,3);
  // weights: 262,144 f4 -> (1024,4)
  cvt_w<<<dim3(1024, 4), 256, 0, stream>>>(wq, whq, wk, whk, wv, whv, wo, who);
  cvt_in<<<dim3(16384, 3), 256, 0, stream>>>(k, Xk, v, Xv, q, Xq);

  // K/V projections (transposed per-head outputs)
  gemm_bk32<1, 1, 0, _Float16><<<GBLK, 512, 0, stream>>>(Xk, whk, bk, KT, nullptr);
  gemm_bk32<0, 1, 0, _Float16><<<GBLK, 512, 0, stream>>>(Xv, whv, bv, VT, nullptr);

  kv_mfma<<<dim3(64, 4), 256, 0, stream>>>(KT, VT, pKV);
  kv_combine<<<1280, 256, 0, stream>>>(pKV, KVTx);   // KVTx over dead Xv

  // Q projection + attention fused (BK32 + global-B-frag epilogue)
  gemm_bk32<1, 0, 1, _Float16><<<GBLK, 512, 0, stream>>>(Xq, whq, bq, att, KVTx);

  // output projection; overwrites all of d_out (Xk/KVTx dead)
  gemm_bk32<0, 0, 0, float><<<GBLK, 512, 0, stream>>>(att, who, bo, out, nullptr);
}

// Round 13
// 262.435 us; speedup vs baseline: 1.3382x; 1.0013x over previous
//
#include <hip/hip_runtime.h>
#include <hip/hip_bf16.h>

typedef _Float16 half8 __attribute__((ext_vector_type(8)));
typedef _Float16 half4 __attribute__((ext_vector_type(4)));
typedef float f32x4 __attribute__((ext_vector_type(4)));

#define KDIM 1024
#define NDIM 1024
#define MROWS 16384   // B*L = 4*4096

#define GLD_LDS16(g, l)                                                  \
  __builtin_amdgcn_global_load_lds(                                      \
      (const __attribute__((address_space(1))) void*)(g),                \
      (__attribute__((address_space(3))) void*)(l), 16, 0, 0)

// ---------------------------------------------------------------------------
// fp32 -> fp16 convert, round-2/7 proven shape (~17 us per 64MB tensor):
// grid-stride, 2x float4 loads + one 16B half8 store per iteration.
// Launched per-tensor, all writing the SAME Xh buffer (L3-hot writes).
// ---------------------------------------------------------------------------
__global__ __launch_bounds__(256)
void cvt_f32_to_f16(const float* __restrict__ src, _Float16* __restrict__ dst,
                    int n8) {
  for (int i = blockIdx.x * 256 + threadIdx.x; i < n8; i += gridDim.x * 256) {
    float4 f0 = ((const float4*)src)[2 * i];
    float4 f1 = ((const float4*)src)[2 * i + 1];
    half8 h;
    h[0] = (_Float16)f0.x; h[1] = (_Float16)f0.y;
    h[2] = (_Float16)f0.z; h[3] = (_Float16)f0.w;
    h[4] = (_Float16)f1.x; h[5] = (_Float16)f1.y;
    h[6] = (_Float16)f1.z; h[7] = (_Float16)f1.w;
    ((half8*)dst)[i] = h;
  }
}

// weights (small): fused 4-tensor, 1 float4/thread
__global__ __launch_bounds__(256)
void cvt_w(const float* __restrict__ s0, _Float16* __restrict__ d0,
           const float* __restrict__ s1, _Float16* __restrict__ d1,
           const float* __restrict__ s2, _Float16* __restrict__ d2,
           const float* __restrict__ s3, _Float16* __restrict__ d3) {
  const float* src;
  _Float16* dst;
  switch (blockIdx.y) {
    case 0: src = s0; dst = d0; break;
    case 1: src = s1; dst = d1; break;
    case 2: src = s2; dst = d2; break;
    default: src = s3; dst = d3; break;
  }
  size_t i = (size_t)blockIdx.x * 256 + threadIdx.x;
  float4 f = ((const float4*)src)[i];
  half4 h;
  h[0] = (_Float16)f.x; h[1] = (_Float16)f.y;
  h[2] = (_Float16)f.z; h[3] = (_Float16)f.w;
  ((half4*)dst)[i] = h;
}

// ---------------------------------------------------------------------------
// BK32 GEMM: Y = act(X @ W^T + bias), fp16 in, fp32 accum. 256x128, BK=32,
// 8 waves, 3-buf 72KB -> 2 blocks/CU, counted-vmcnt(3) 2-ahead pipeline.
// SWIZZLE AXIS FIX (r11 quad arithmetic, now applied to the fp16 path):
// 64B LDS rows have 2 bank phases, so conflict-free XOR is
// slot ^= (row>>1)&3. gld_lds inverse source gsl=(lane&3)^((lane>>3)&3);
// ds_read rsl=((lane>>4)^((lane>>1)&3))<<4. (row&3 axis = 4-way conflicts;
// F32A probe r10->r11: 6.3M -> 131K conflicts with this axis.)
// ACT: 0 none, 1 elu+1. TRANS: 1 = per-head transposed fp16 (half4).
// FUSE: 1 = linear-attention epilogue (Ct overlays smem, 256B rows with
// row&7 axis = already correct; KVTx B-frags direct from global, L2-hot).
// ---------------------------------------------------------------------------
template <int ACT, int TRANS, int FUSE, typename TOUT>
__global__ __launch_bounds__(512, 2)
void gemm_bk32(const _Float16* __restrict__ X, const _Float16* __restrict__ W,
               const float* __restrict__ bias, TOUT* __restrict__ Y,
               const _Float16* __restrict__ KVTx) {
  constexpr int BM = 256, BN = 128, BK = 32;
  __shared__ char smem[73728];                    // 72 KB
  _Float16* As = (_Float16*)smem;                 // 48 KB (3 x 16 KB)
  _Float16* Bs = (_Float16*)(smem + 49152);       // 24 KB (3 x 8 KB)

  const int tid  = threadIdx.x;
  const int lane = tid & 63;
  const int w    = tid >> 6;
  const int wm   = w >> 1;
  const int wn   = w & 1;

  const int bid = blockIdx.x;
  const int wid = (bid & 7) * 64 + (bid >> 3);
  const int m0  = (wid >> 3) * BM;
  const int n0  = (wid & 7) * BN;

  const int lrw = lane >> 2;                       // 0..15 (row in 16-row grp)
  const int gsl = (lane & 3) ^ ((lane >> 3) & 3);  // inverse slot, (row>>1)&3
  const _Float16* gA = X + (size_t)(m0 + w * 16 + lrw) * KDIM + gsl * 8;
  const _Float16* gB = W + (size_t)(n0 + w * 16 + lrw) * KDIM + gsl * 8;

#define STAGE32(kt, bidx)                                                     \
  {                                                                           \
    const int k0s = (kt) * BK;                                                \
    _Float16* la = As + (bidx) * (BM * BK) + (w * 16) * BK;                   \
    _Float16* lb = Bs + (bidx) * (BN * BK) + (w * 16) * BK;                   \
    GLD_LDS16(gA + k0s, la);                                                  \
    GLD_LDS16(gA + (size_t)128 * KDIM + k0s, la + 128 * BK);                  \
    GLD_LDS16(gB + k0s, lb);                                                  \
  }

  const int rsl = ((lane >> 4) ^ ((lane >> 1) & 3)) << 4;

  f32x4 acc[4][4] = {};

  STAGE32(0, 0);
  STAGE32(1, 1);
  asm volatile("s_waitcnt vmcnt(3)" ::: "memory");
  asm volatile("s_barrier" ::: "memory");

  int bc = 0;
  for (int t = 0; t < 32; ++t) {
    int bs = bc + 2; if (bs >= 3) bs -= 3;
    const char* Ab = (const char*)As + bc * (BM * BK * 2);
    const char* Bb = (const char*)Bs + bc * (BN * BK * 2);

    half8 afr[4], bfr[4];
#pragma unroll
    for (int mi = 0; mi < 4; ++mi) {
      int row = wm * 64 + mi * 16 + (lane & 15);
      afr[mi] = *(const half8*)(Ab + row * 64 + rsl);
    }
#pragma unroll
    for (int ni = 0; ni < 4; ++ni) {
      int row = wn * 64 + ni * 16 + (lane & 15);
      bfr[ni] = *(const half8*)(Bb + row * 64 + rsl);
    }

    if (t < 30) STAGE32(t + 2, bs);

    __builtin_amdgcn_s_setprio(1);
#pragma unroll
    for (int mi = 0; mi < 4; ++mi)
#pragma unroll
      for (int ni = 0; ni < 4; ++ni)
        acc[mi][ni] = __builtin_amdgcn_mfma_f32_16x16x32_f16(
            afr[mi], bfr[ni], acc[mi][ni], 0, 0, 0);
    __builtin_amdgcn_s_setprio(0);

    if (t < 30) {
      asm volatile("s_waitcnt vmcnt(3)" ::: "memory");
      asm volatile("s_barrier" ::: "memory");
    } else if (t == 30) {
      asm volatile("s_waitcnt vmcnt(0)" ::: "memory");
      asm volatile("s_barrier" ::: "memory");
    }
    ++bc; if (bc == 3) bc = 0;
  }
#undef STAGE32

  if constexpr (FUSE) {
    // ---- fused linear-attention epilogue (Ct overlays smem; B from global)
    __syncthreads();
    _Float16* Ct = (_Float16*)smem;   // [256 rows][128 cols], 256B rows
#pragma unroll
    for (int ni = 0; ni < 4; ++ni) {
      int cl   = wn * 64 + ni * 16 + (lane & 15);
      float bv = bias[n0 + cl];
#pragma unroll
      for (int mi = 0; mi < 4; ++mi) {
#pragma unroll
        for (int i = 0; i < 4; ++i) {
          int row = wm * 64 + mi * 16 + ((lane >> 4) << 2) + i;
          float v = acc[mi][ni][i] + bv;
          v = (v > 0.f) ? (v + 1.f) : __expf(v);
          int byte = row * 256 + cl * 2;
          byte ^= (row & 7) << 4;
          *(_Float16*)((char*)Ct + byte) = (_Float16)v;
        }
      }
    }
    __syncthreads();
    const int bh0 = ((m0 >> 12) << 4) + (n0 >> 6);
    const _Float16* kvp = KVTx + (size_t)(bh0 + wn) * 5120;
    f32x4 acc2[4][5] = {};
#pragma unroll
    for (int kk = 0; kk < 2; ++kk) {
      half8 afr2[4], bfr2[5];
#pragma unroll
      for (int m = 0; m < 4; ++m) {
        int row  = wm * 64 + m * 16 + (lane & 15);
        int byte = row * 256 + wn * 128 + kk * 64 + ((lane >> 4) << 4);
        byte ^= (row & 7) << 4;
        afr2[m] = *(const half8*)((const char*)Ct + byte);
      }
#pragma unroll
      for (int n = 0; n < 5; ++n) {
        int row = n * 16 + (lane & 15);
        bfr2[n] = *(const half8*)(kvp + row * 64 + kk * 32 + ((lane >> 4) << 3));
      }
#pragma unroll
      for (int m = 0; m < 4; ++m)
#pragma unroll
        for (int n = 0; n < 5; ++n)
          acc2[m][n] = __builtin_amdgcn_mfma_f32_16x16x32_f16(
              afr2[m], bfr2[n], acc2[m][n], 0, 0, 0);
    }
#pragma unroll
    for (int m = 0; m < 4; ++m) {
#pragma unroll
      for (int i = 0; i < 4; ++i) {
        float dn = __shfl(acc2[m][4][i], lane & 48);
        float z  = 1.f / (dn + 1e-6f);
        size_t row = (size_t)m0 + wm * 64 + m * 16 + ((lane >> 4) << 2) + i;
#pragma unroll
        for (int n = 0; n < 4; ++n) {
          int col = n0 + wn * 64 + n * 16 + (lane & 15);
          Y[row * NDIM + col] = (TOUT)(acc2[m][n][i] * z);
        }
      }
    }
    return;
  }

#pragma unroll
  for (int ni = 0; ni < 4; ++ni) {
    int col  = n0 + wn * 64 + ni * 16 + (lane & 15);
    float bv = bias[col];
#pragma unroll
    for (int mi = 0; mi < 4; ++mi) {
      int r0 = m0 + wm * 64 + mi * 16 + ((lane >> 4) << 2);
      if constexpr (TRANS) {
        int b  = r0 >> 12;
        int l0 = r0 & 4095;
        half4 hv;
#pragma unroll
        for (int i = 0; i < 4; ++i) {
          float v = acc[mi][ni][i] + bv;
          if constexpr (ACT == 1) v = (v > 0.f) ? (v + 1.f) : __expf(v);
          hv[i] = (_Float16)v;
        }
        *(half4*)((_Float16*)Y + ((size_t)(b * 1024 + col)) * 4096 + l0) = hv;
      } else {
#pragma unroll
        for (int i = 0; i < 4; ++i) {
          float v = acc[mi][ni][i] + bv;
          if constexpr (ACT == 1) v = (v > 0.f) ? (v + 1.f) : __expf(v);
          Y[(size_t)(r0 + i) * NDIM + col] = (TOUT)v;
        }
      }
    }
  }
}

// ---------------------------------------------------------------------------
// kv_mfma: per (bh, chunk of 1024 l): partial C'[e][d] = sum_l VT[e][l]*KT[d][l]
// A = VT rows + synthesized ones-row (m-frag 4 -> Ksum); B = KT rows.
// (128B LDS rows -> row&7 swizzle axis is correct here.)
// ---------------------------------------------------------------------------
__global__ __launch_bounds__(256, 2)
void kv_mfma(const _Float16* __restrict__ KT, const _Float16* __restrict__ VT,
             _Float16* __restrict__ pKV) {
  const int bh = blockIdx.x;      // 0..63
  const int ch = blockIdx.y;      // 0..3
  const int tid  = threadIdx.x;
  const int lane = tid & 63;
  const int w    = tid >> 6;

  __shared__ _Float16 As[64 * 64];
  __shared__ _Float16 Bs[64 * 64];

  const int lr = lane >> 3;
  const int ls = (lane & 7) ^ lr;
  const size_t lbase = (size_t)ch * 1024 + ls * 8;
  const _Float16* gA = VT + (size_t)(bh * 64 + w * 16 + lr) * 4096 + lbase;
  const _Float16* gB = KT + (size_t)(bh * 64 + w * 16 + lr) * 4096 + lbase;
  _Float16* ldsA = As + (w * 16) * 64;
  _Float16* ldsB = Bs + (w * 16) * 64;

  half8 aones;
#pragma unroll
  for (int j = 0; j < 8; ++j) aones[j] = (lane & 15) == 0 ? (_Float16)1.0f : (_Float16)0.0f;

  f32x4 acc[5] = {};

  for (int k0 = 0; k0 < 1024; k0 += 64) {
    __syncthreads();
#pragma unroll
    for (int c = 0; c < 2; ++c) {
      GLD_LDS16(gA + k0 + (size_t)(c * 8) * 4096, ldsA + c * 8 * 64);
      GLD_LDS16(gB + k0 + (size_t)(c * 8) * 4096, ldsB + c * 8 * 64);
    }
    __syncthreads();

    half8 afr[4][2], bfr[2];
#pragma unroll
    for (int m = 0; m < 4; ++m)
#pragma unroll
      for (int kk = 0; kk < 2; ++kk) {
        int row  = m * 16 + (lane & 15);
        int byte = row * 128 + ((lane >> 4) << 4) + kk * 64;
        byte ^= (row & 7) << 4;
        afr[m][kk] = *(const half8*)((const char*)As + byte);
      }
#pragma unroll
    for (int kk = 0; kk < 2; ++kk) {
      int row  = w * 16 + (lane & 15);
      int byte = row * 128 + ((lane >> 4) << 4) + kk * 64;
      byte ^= (row & 7) << 4;
      bfr[kk] = *(const half8*)((const char*)Bs + byte);
    }
#pragma unroll
    for (int kk = 0; kk < 2; ++kk) {
#pragma unroll
      for (int m = 0; m < 4; ++m)
        acc[m] = __builtin_amdgcn_mfma_f32_16x16x32_f16(afr[m][kk], bfr[kk],
                                                        acc[m], 0, 0, 0);
      acc[4] = __builtin_amdgcn_mfma_f32_16x16x32_f16(aones, bfr[kk],
                                                      acc[4], 0, 0, 0);
    }
  }

  _Float16* outp = pKV + ((size_t)ch * 64 + bh) * 5120;
  const int col = w * 16 + (lane & 15);
#pragma unroll
  for (int m = 0; m < 5; ++m) {
#pragma unroll
    for (int i = 0; i < 4; ++i) {
      int row = m * 16 + ((lane >> 4) << 2) + i;
      outp[row * 64 + col] = (_Float16)acc[m][i];
    }
  }
}

// ---------------------------------------------------------------------------
// Combine 4 fp16 partials -> KVTx fp16 [64 bh][80 rows][64 cols]
// ---------------------------------------------------------------------------
__global__ __launch_bounds__(256)
void kv_combine(const _Float16* __restrict__ pKV, _Float16* __restrict__ KVTx) {
  int g = blockIdx.x * 256 + threadIdx.x;   // 0..327679
  int bh = g / 5120;
  int j  = g - bh * 5120;
  float s = 0.f;
#pragma unroll
  for (int ch = 0; ch < 4; ++ch)
    s += (float)pKV[((size_t)ch * 64 + bh) * 5120 + j];
  KVTx[(size_t)bh * 5120 + j] = (_Float16)s;
}

// ---------------------------------------------------------------------------
extern "C" void kernel_launch(void* const* d_in, const int* in_sizes, int n_in,
                              void* d_out, int out_size, void* d_ws, size_t ws_size,
                              hipStream_t stream) {
  const float* q  = (const float*)d_in[0];
  const float* k  = (const float*)d_in[1];
  const float* v  = (const float*)d_in[2];
  const float* wq = (const float*)d_in[3];
  const float* bq = (const float*)d_in[4];
  const float* wk = (const float*)d_in[5];
  const float* bk = (const float*)d_in[6];
  const float* wv = (const float*)d_in[7];
  const float* bv = (const float*)d_in[8];
  const float* wo = (const float*)d_in[9];
  const float* bo = (const float*)d_in[10];
  float* out = (float*)d_out;

  char* ws = (char*)d_ws;
  _Float16* Xh   = (_Float16*)(ws);                      // 0..32MB (reused q,k,v)
  _Float16* KT   = (_Float16*)(ws + 33554432);           // 32..64MB
  _Float16* VT   = (_Float16*)(ws + 67108864);           // 64..96MB
  _Float16* pKV  = (_Float16*)(ws + 100663296);          // 2.62MB over whk/whv
  _Float16* whk  = (_Float16*)(ws + 100663296);          // 2MB (dies after K-gemm)
  _Float16* whv  = (_Float16*)(ws + 102760448);          // 2MB (dies after V-gemm)
  _Float16* whq  = (_Float16*)(ws + 104857600);          // 2MB
  _Float16* who  = (_Float16*)(ws + 106954752);          // 2MB (lives to the end)
  _Float16* KVTx = (_Float16*)(ws + 109051904);          // 655KB
  _Float16* att  = KT;                                   // reuse KT after KV built

  const int N8_BIG = MROWS * KDIM / 8;             // 2,097,152
  const int GBLK = (MROWS / 256) * (NDIM / 128);   // 512 blocks

  // weights (fused small): 262,144 f4 -> (1024,4)
  cvt_w<<<dim3(1024, 4), 256, 0, stream>>>(wq, whq, wk, whk, wv, whv, wo, who);

  // K projection
  cvt_f32_to_f16<<<2048, 256, 0, stream>>>(k, Xh, N8_BIG);
  gemm_bk32<1, 1, 0, _Float16><<<GBLK, 512, 0, stream>>>(Xh, whk, bk, KT, nullptr);
  // V projection
  cvt_f32_to_f16<<<2048, 256, 0, stream>>>(v, Xh, N8_BIG);
  gemm_bk32<0, 1, 0, _Float16><<<GBLK, 512, 0, stream>>>(Xh, whv, bv, VT, nullptr);

  kv_mfma<<<dim3(64, 4), 256, 0, stream>>>(KT, VT, pKV);
  kv_combine<<<1280, 256, 0, stream>>>(pKV, KVTx);

  // Q projection + attention fused
  cvt_f32_to_f16<<<2048, 256, 0, stream>>>(q, Xh, N8_BIG);
  gemm_bk32<1, 0, 1, _Float16><<<GBLK, 512, 0, stream>>>(Xh, whq, bq, att, KVTx);

  // output projection -> d_out
  gemm_bk32<0, 0, 0, float><<<GBLK, 512, 0, stream>>>(att, who, bo, out, nullptr);
}

// Round 14
// 256.506 us; speedup vs baseline: 1.3691x; 1.0231x over previous
//
#include <hip/hip_runtime.h>
#include <hip/hip_bf16.h>

typedef _Float16 half8 __attribute__((ext_vector_type(8)));
typedef _Float16 half4 __attribute__((ext_vector_type(4)));
typedef float f32x4 __attribute__((ext_vector_type(4)));

#define KDIM 1024
#define NDIM 1024
#define MROWS 16384   // B*L = 4*4096

#define GLD_LDS16(g, l)                                                  \
  __builtin_amdgcn_global_load_lds(                                      \
      (const __attribute__((address_space(1))) void*)(g),                \
      (__attribute__((address_space(3))) void*)(l), 16, 0, 0)

// ---------------------------------------------------------------------------
// fp32 -> fp16 convert (r13 shape)
// ---------------------------------------------------------------------------
__global__ __launch_bounds__(256)
void cvt_f32_to_f16(const float* __restrict__ src, _Float16* __restrict__ dst,
                    int n8) {
  for (int i = blockIdx.x * 256 + threadIdx.x; i < n8; i += gridDim.x * 256) {
    float4 f0 = ((const float4*)src)[2 * i];
    float4 f1 = ((const float4*)src)[2 * i + 1];
    half8 h;
    h[0] = (_Float16)f0.x; h[1] = (_Float16)f0.y;
    h[2] = (_Float16)f0.z; h[3] = (_Float16)f0.w;
    h[4] = (_Float16)f1.x; h[5] = (_Float16)f1.y;
    h[6] = (_Float16)f1.z; h[7] = (_Float16)f1.w;
    ((half8*)dst)[i] = h;
  }
}

__global__ __launch_bounds__(256)
void cvt_w(const float* __restrict__ s0, _Float16* __restrict__ d0,
           const float* __restrict__ s1, _Float16* __restrict__ d1,
           const float* __restrict__ s2, _Float16* __restrict__ d2,
           const float* __restrict__ s3, _Float16* __restrict__ d3) {
  const float* src;
  _Float16* dst;
  switch (blockIdx.y) {
    case 0: src = s0; dst = d0; break;
    case 1: src = s1; dst = d1; break;
    case 2: src = s2; dst = d2; break;
    default: src = s3; dst = d3; break;
  }
  size_t i = (size_t)blockIdx.x * 256 + threadIdx.x;
  float4 f = ((const float4*)src)[i];
  half4 h;
  h[0] = (_Float16)f.x; h[1] = (_Float16)f.y;
  h[2] = (_Float16)f.z; h[3] = (_Float16)f.w;
  ((half4*)dst)[i] = h;
}

// ---------------------------------------------------------------------------
// 8-PHASE 256x256 GEMM (m201-style, derived ledger) for K/V projections.
// BM=BN=256, BK=64 as 2 K-halves of 32; 8 waves (2M x 4N; 128x64/wave).
// LDS = [2 dbuf][2 kh][256 rows x 32 k] per operand = 128 KB total.
// Per tile T (dbuf d=T&1): 4 phases
//   p0: vmcnt(4)+barrier; read A(kh0,mh0) 8 + B(kh0) 4; stage A-kh0(T+1); 16 MFMA
//   p1:                    read A(kh0,mh1) 4;           stage B-kh0(T+1); 16 MFMA
//   p2: vmcnt(4)+barrier; read A(kh1,mh0) 8 + B(kh1) 4; stage A-kh1(T+1); 16 MFMA
//   p3:                    read A(kh1,mh1) 4;           stage B-kh1(T+1); 16 MFMA
// Outstanding gld_lds = 8 at each tile entry (4 half-tiles x 2 instr);
// vmcnt(4) completes exactly the oldest half-tile pair needed. Never 0
// mid-loop; last tile drains via vmcnt(0) at p2. All T-reads hit dbuf[d],
// all T-stages write dbuf[d^1]; p0 barrier joins waves past T-1 -> race-free.
// Swizzle: 64B rows, involution slot ^= (row>>1)&3 on both sides (r13 axis).
// Epilogue: per-head transposed fp16 (TRANS) with ACT (elu+1 for K).
// ---------------------------------------------------------------------------
template <int ACT>
__global__ __launch_bounds__(512, 2)
void gemm_8ph(const _Float16* __restrict__ X, const _Float16* __restrict__ W,
              const float* __restrict__ bias, _Float16* __restrict__ Y) {
  __shared__ _Float16 As[2 * 2 * 8192];   // 64 KB
  __shared__ _Float16 Bs[2 * 2 * 8192];   // 64 KB

  const int tid  = threadIdx.x;
  const int lane = tid & 63;
  const int w    = tid >> 6;        // 0..7
  const int wm   = w >> 2;          // 0..1 -> rows wm*128
  const int wn   = w & 3;           // 0..3 -> cols wn*64

  const int bid = blockIdx.x;
  const int wid = (bid & 7) * 32 + (bid >> 3);   // 256 blocks, bijective
  const int m0  = (wid >> 2) * 256;
  const int n0  = (wid & 3) * 256;

  // staging: wave w covers rows w*32 + j*16 + (lane>>2); 16B slot lane&3;
  // inverse-swizzled global slot gsl = (lane&3) ^ ((row>>1)&3) = ^(lane>>3)&3
  const int srow = lane >> 2;
  const int gsl  = (lane & 3) ^ ((lane >> 3) & 3);
  const _Float16* gA = X + (size_t)(m0 + w * 32 + srow) * KDIM + gsl * 8;
  const _Float16* gB = W + (size_t)(n0 + w * 32 + srow) * KDIM + gsl * 8;

#define STG(OPD, GSRC, T, KH, D)                                             \
  {                                                                          \
    _Float16* ldst = OPD + ((D) * 2 + (KH)) * 8192 + (w * 32) * 32;          \
    const _Float16* gs = GSRC + (size_t)(T) * 64 + (KH) * 32;                \
    GLD_LDS16(gs, ldst);                                                     \
    GLD_LDS16(gs + (size_t)16 * KDIM, ldst + 16 * 32);                       \
  }

  // frag reads: row r; byte = blk*16384 + r*64 + rsl, rsl = ((lane>>4)^f)<<4
  const int rsl = ((lane >> 4) ^ ((lane >> 1) & 3)) << 4;

#define RDA(DST, D, KH, MH)                                                  \
  _Pragma("unroll") for (int mi = 0; mi < 4; ++mi) {                         \
    int r = wm * 128 + (MH) * 64 + mi * 16 + (lane & 15);                    \
    DST[mi] = *(const half8*)((const char*)As + ((D) * 2 + (KH)) * 16384 +   \
                              r * 64 + rsl);                                 \
  }
#define RDB(D, KH)                                                           \
  _Pragma("unroll") for (int ni = 0; ni < 4; ++ni) {                         \
    int r = wn * 64 + ni * 16 + (lane & 15);                                 \
    b[ni] = *(const half8*)((const char*)Bs + ((D) * 2 + (KH)) * 16384 +     \
                            r * 64 + rsl);                                   \
  }
#define MM(AV, MH)                                                           \
  __builtin_amdgcn_s_setprio(1);                                             \
  _Pragma("unroll") for (int mi = 0; mi < 4; ++mi)                           \
    _Pragma("unroll") for (int ni = 0; ni < 4; ++ni)                         \
      acc[(MH) * 4 + mi][ni] = __builtin_amdgcn_mfma_f32_16x16x32_f16(       \
          AV[mi], b[ni], acc[(MH) * 4 + mi][ni], 0, 0, 0);                   \
  __builtin_amdgcn_s_setprio(0);

  f32x4 acc[8][4] = {};
  half8 a0[4], a1[4], b[4];

  // prologue: tile 0 halves in order [A-kh0, B-kh0, A-kh1, B-kh1] -> dbuf 0
  STG(As, gA, 0, 0, 0); STG(Bs, gB, 0, 0, 0);
  STG(As, gA, 0, 1, 0); STG(Bs, gB, 0, 1, 0);

  for (int T = 0; T < 16; ++T) {
    const int d = T & 1, e = d ^ 1;
    // ---- p0: kh0, m-half0
    asm volatile("s_waitcnt vmcnt(4)" ::: "memory");   // A-kh0,B-kh0 landed
    asm volatile("s_barrier" ::: "memory");
    RDA(a0, d, 0, 0);
    RDB(d, 0);
    if (T < 15) STG(As, gA, T + 1, 0, e);
    MM(a0, 0);
    // ---- p1: kh0, m-half1
    RDA(a1, d, 0, 1);
    if (T < 15) STG(Bs, gB, T + 1, 0, e);
    MM(a1, 1);
    // ---- p2: kh1, m-half0
    if (T < 15) { asm volatile("s_waitcnt vmcnt(4)" ::: "memory"); }
    else        { asm volatile("s_waitcnt vmcnt(0)" ::: "memory"); }
    asm volatile("s_barrier" ::: "memory");
    RDA(a0, d, 1, 0);
    RDB(d, 1);
    if (T < 15) STG(As, gA, T + 1, 1, e);
    MM(a0, 0);
    // ---- p3: kh1, m-half1
    RDA(a1, d, 1, 1);
    if (T < 15) STG(Bs, gB, T + 1, 1, e);
    MM(a1, 1);
  }
#undef STG
#undef RDA
#undef RDB
#undef MM

  // epilogue: bias + act + per-head transposed store (half4 over 4 rows)
#pragma unroll
  for (int ni = 0; ni < 4; ++ni) {
    int col  = n0 + wn * 64 + ni * 16 + (lane & 15);
    float bv = bias[col];
#pragma unroll
    for (int mi = 0; mi < 8; ++mi) {
      int r0 = m0 + wm * 128 + mi * 16 + ((lane >> 4) << 2);
      int bb = r0 >> 12;
      int l0 = r0 & 4095;
      half4 hv;
#pragma unroll
      for (int i = 0; i < 4; ++i) {
        float v = acc[mi][ni][i] + bv;
        if constexpr (ACT == 1) v = (v > 0.f) ? (v + 1.f) : __expf(v);
        hv[i] = (_Float16)v;
      }
      *(half4*)(Y + ((size_t)(bb * 1024 + col)) * 4096 + l0) = hv;
    }
  }
}

// ---------------------------------------------------------------------------
// BK32 GEMM (r13): 256x128, BK=32, 3-buf 72KB, 2 blocks/CU, vmcnt(3) 2-ahead.
// Used for Q-fused and output projections this round.
// ---------------------------------------------------------------------------
template <int ACT, int TRANS, int FUSE, typename TOUT>
__global__ __launch_bounds__(512, 2)
void gemm_bk32(const _Float16* __restrict__ X, const _Float16* __restrict__ W,
               const float* __restrict__ bias, TOUT* __restrict__ Y,
               const _Float16* __restrict__ KVTx) {
  constexpr int BM = 256, BN = 128, BK = 32;
  __shared__ char smem[73728];                    // 72 KB
  _Float16* As = (_Float16*)smem;                 // 48 KB (3 x 16 KB)
  _Float16* Bs = (_Float16*)(smem + 49152);       // 24 KB (3 x 8 KB)

  const int tid  = threadIdx.x;
  const int lane = tid & 63;
  const int w    = tid >> 6;
  const int wm   = w >> 1;
  const int wn   = w & 1;

  const int bid = blockIdx.x;
  const int wid = (bid & 7) * 64 + (bid >> 3);
  const int m0  = (wid >> 3) * BM;
  const int n0  = (wid & 7) * BN;

  const int lrw = lane >> 2;
  const int gsl = (lane & 3) ^ ((lane >> 3) & 3);
  const _Float16* gA = X + (size_t)(m0 + w * 16 + lrw) * KDIM + gsl * 8;
  const _Float16* gB = W + (size_t)(n0 + w * 16 + lrw) * KDIM + gsl * 8;

#define STAGE32(kt, bidx)                                                     \
  {                                                                           \
    const int k0s = (kt) * BK;                                                \
    _Float16* la = As + (bidx) * (BM * BK) + (w * 16) * BK;                   \
    _Float16* lb = Bs + (bidx) * (BN * BK) + (w * 16) * BK;                   \
    GLD_LDS16(gA + k0s, la);                                                  \
    GLD_LDS16(gA + (size_t)128 * KDIM + k0s, la + 128 * BK);                  \
    GLD_LDS16(gB + k0s, lb);                                                  \
  }

  const int rsl = ((lane >> 4) ^ ((lane >> 1) & 3)) << 4;

  f32x4 acc[4][4] = {};

  STAGE32(0, 0);
  STAGE32(1, 1);
  asm volatile("s_waitcnt vmcnt(3)" ::: "memory");
  asm volatile("s_barrier" ::: "memory");

  int bc = 0;
  for (int t = 0; t < 32; ++t) {
    int bs = bc + 2; if (bs >= 3) bs -= 3;
    const char* Ab = (const char*)As + bc * (BM * BK * 2);
    const char* Bb = (const char*)Bs + bc * (BN * BK * 2);

    half8 afr[4], bfr[4];
#pragma unroll
    for (int mi = 0; mi < 4; ++mi) {
      int row = wm * 64 + mi * 16 + (lane & 15);
      afr[mi] = *(const half8*)(Ab + row * 64 + rsl);
    }
#pragma unroll
    for (int ni = 0; ni < 4; ++ni) {
      int row = wn * 64 + ni * 16 + (lane & 15);
      bfr[ni] = *(const half8*)(Bb + row * 64 + rsl);
    }

    if (t < 30) STAGE32(t + 2, bs);

    __builtin_amdgcn_s_setprio(1);
#pragma unroll
    for (int mi = 0; mi < 4; ++mi)
#pragma unroll
      for (int ni = 0; ni < 4; ++ni)
        acc[mi][ni] = __builtin_amdgcn_mfma_f32_16x16x32_f16(
            afr[mi], bfr[ni], acc[mi][ni], 0, 0, 0);
    __builtin_amdgcn_s_setprio(0);

    if (t < 30) {
      asm volatile("s_waitcnt vmcnt(3)" ::: "memory");
      asm volatile("s_barrier" ::: "memory");
    } else if (t == 30) {
      asm volatile("s_waitcnt vmcnt(0)" ::: "memory");
      asm volatile("s_barrier" ::: "memory");
    }
    ++bc; if (bc == 3) bc = 0;
  }
#undef STAGE32

  if constexpr (FUSE) {
    __syncthreads();
    _Float16* Ct = (_Float16*)smem;   // [256 rows][128 cols], 256B rows
#pragma unroll
    for (int ni = 0; ni < 4; ++ni) {
      int cl   = wn * 64 + ni * 16 + (lane & 15);
      float bv = bias[n0 + cl];
#pragma unroll
      for (int mi = 0; mi < 4; ++mi) {
#pragma unroll
        for (int i = 0; i < 4; ++i) {
          int row = wm * 64 + mi * 16 + ((lane >> 4) << 2) + i;
          float v = acc[mi][ni][i] + bv;
          v = (v > 0.f) ? (v + 1.f) : __expf(v);
          int byte = row * 256 + cl * 2;
          byte ^= (row & 7) << 4;
          *(_Float16*)((char*)Ct + byte) = (_Float16)v;
        }
      }
    }
    __syncthreads();
    const int bh0 = ((m0 >> 12) << 4) + (n0 >> 6);
    const _Float16* kvp = KVTx + (size_t)(bh0 + wn) * 5120;
    f32x4 acc2[4][5] = {};
#pragma unroll
    for (int kk = 0; kk < 2; ++kk) {
      half8 afr2[4], bfr2[5];
#pragma unroll
      for (int m = 0; m < 4; ++m) {
        int row  = wm * 64 + m * 16 + (lane & 15);
        int byte = row * 256 + wn * 128 + kk * 64 + ((lane >> 4) << 4);
        byte ^= (row & 7) << 4;
        afr2[m] = *(const half8*)((const char*)Ct + byte);
      }
#pragma unroll
      for (int n = 0; n < 5; ++n) {
        int row = n * 16 + (lane & 15);
        bfr2[n] = *(const half8*)(kvp + row * 64 + kk * 32 + ((lane >> 4) << 3));
      }
#pragma unroll
      for (int m = 0; m < 4; ++m)
#pragma unroll
        for (int n = 0; n < 5; ++n)
          acc2[m][n] = __builtin_amdgcn_mfma_f32_16x16x32_f16(
              afr2[m], bfr2[n], acc2[m][n], 0, 0, 0);
    }
#pragma unroll
    for (int m = 0; m < 4; ++m) {
#pragma unroll
      for (int i = 0; i < 4; ++i) {
        float dn = __shfl(acc2[m][4][i], lane & 48);
        float z  = 1.f / (dn + 1e-6f);
        size_t row = (size_t)m0 + wm * 64 + m * 16 + ((lane >> 4) << 2) + i;
#pragma unroll
        for (int n = 0; n < 4; ++n) {
          int col = n0 + wn * 64 + n * 16 + (lane & 15);
          Y[row * NDIM + col] = (TOUT)(acc2[m][n][i] * z);
        }
      }
    }
    return;
  }

#pragma unroll
  for (int ni = 0; ni < 4; ++ni) {
    int col  = n0 + wn * 64 + ni * 16 + (lane & 15);
    float bv = bias[col];
#pragma unroll
    for (int mi = 0; mi < 4; ++mi) {
      int r0 = m0 + wm * 64 + mi * 16 + ((lane >> 4) << 2);
      if constexpr (TRANS) {
        int b  = r0 >> 12;
        int l0 = r0 & 4095;
        half4 hv;
#pragma unroll
        for (int i = 0; i < 4; ++i) {
          float v = acc[mi][ni][i] + bv;
          if constexpr (ACT == 1) v = (v > 0.f) ? (v + 1.f) : __expf(v);
          hv[i] = (_Float16)v;
        }
        *(half4*)((_Float16*)Y + ((size_t)(b * 1024 + col)) * 4096 + l0) = hv;
      } else {
#pragma unroll
        for (int i = 0; i < 4; ++i) {
          float v = acc[mi][ni][i] + bv;
          if constexpr (ACT == 1) v = (v > 0.f) ? (v + 1.f) : __expf(v);
          Y[(size_t)(r0 + i) * NDIM + col] = (TOUT)v;
        }
      }
    }
  }
}

// ---------------------------------------------------------------------------
// kv_mfma: per (bh, chunk of 1024 l): partial C'[e][d] = sum_l VT[e][l]*KT[d][l]
// ---------------------------------------------------------------------------
__global__ __launch_bounds__(256, 2)
void kv_mfma(const _Float16* __restrict__ KT, const _Float16* __restrict__ VT,
             _Float16* __restrict__ pKV) {
  const int bh = blockIdx.x;      // 0..63
  const int ch = blockIdx.y;      // 0..3
  const int tid  = threadIdx.x;
  const int lane = tid & 63;
  const int w    = tid >> 6;

  __shared__ _Float16 As[64 * 64];
  __shared__ _Float16 Bs[64 * 64];

  const int lr = lane >> 3;
  const int ls = (lane & 7) ^ lr;
  const size_t lbase = (size_t)ch * 1024 + ls * 8;
  const _Float16* gA = VT + (size_t)(bh * 64 + w * 16 + lr) * 4096 + lbase;
  const _Float16* gB = KT + (size_t)(bh * 64 + w * 16 + lr) * 4096 + lbase;
  _Float16* ldsA = As + (w * 16) * 64;
  _Float16* ldsB = Bs + (w * 16) * 64;

  half8 aones;
#pragma unroll
  for (int j = 0; j < 8; ++j) aones[j] = (lane & 15) == 0 ? (_Float16)1.0f : (_Float16)0.0f;

  f32x4 acc[5] = {};

  for (int k0 = 0; k0 < 1024; k0 += 64) {
    __syncthreads();
#pragma unroll
    for (int c = 0; c < 2; ++c) {
      GLD_LDS16(gA + k0 + (size_t)(c * 8) * 4096, ldsA + c * 8 * 64);
      GLD_LDS16(gB + k0 + (size_t)(c * 8) * 4096, ldsB + c * 8 * 64);
    }
    __syncthreads();

    half8 afr[4][2], bfr[2];
#pragma unroll
    for (int m = 0; m < 4; ++m)
#pragma unroll
      for (int kk = 0; kk < 2; ++kk) {
        int row  = m * 16 + (lane & 15);
        int byte = row * 128 + ((lane >> 4) << 4) + kk * 64;
        byte ^= (row & 7) << 4;
        afr[m][kk] = *(const half8*)((const char*)As + byte);
      }
#pragma unroll
    for (int kk = 0; kk < 2; ++kk) {
      int row  = w * 16 + (lane & 15);
      int byte = row * 128 + ((lane >> 4) << 4) + kk * 64;
      byte ^= (row & 7) << 4;
      bfr[kk] = *(const half8*)((const char*)Bs + byte);
    }
#pragma unroll
    for (int kk = 0; kk < 2; ++kk) {
#pragma unroll
      for (int m = 0; m < 4; ++m)
        acc[m] = __builtin_amdgcn_mfma_f32_16x16x32_f16(afr[m][kk], bfr[kk],
                                                        acc[m], 0, 0, 0);
      acc[4] = __builtin_amdgcn_mfma_f32_16x16x32_f16(aones, bfr[kk],
                                                      acc[4], 0, 0, 0);
    }
  }

  _Float16* outp = pKV + ((size_t)ch * 64 + bh) * 5120;
  const int col = w * 16 + (lane & 15);
#pragma unroll
  for (int m = 0; m < 5; ++m) {
#pragma unroll
    for (int i = 0; i < 4; ++i) {
      int row = m * 16 + ((lane >> 4) << 2) + i;
      outp[row * 64 + col] = (_Float16)acc[m][i];
    }
  }
}

// ---------------------------------------------------------------------------
__global__ __launch_bounds__(256)
void kv_combine(const _Float16* __restrict__ pKV, _Float16* __restrict__ KVTx) {
  int g = blockIdx.x * 256 + threadIdx.x;   // 0..327679
  int bh = g / 5120;
  int j  = g - bh * 5120;
  float s = 0.f;
#pragma unroll
  for (int ch = 0; ch < 4; ++ch)
    s += (float)pKV[((size_t)ch * 64 + bh) * 5120 + j];
  KVTx[(size_t)bh * 5120 + j] = (_Float16)s;
}

// ---------------------------------------------------------------------------
extern "C" void kernel_launch(void* const* d_in, const int* in_sizes, int n_in,
                              void* d_out, int out_size, void* d_ws, size_t ws_size,
                              hipStream_t stream) {
  const float* q  = (const float*)d_in[0];
  const float* k  = (const float*)d_in[1];
  const float* v  = (const float*)d_in[2];
  const float* wq = (const float*)d_in[3];
  const float* bq = (const float*)d_in[4];
  const float* wk = (const float*)d_in[5];
  const float* bk = (const float*)d_in[6];
  const float* wv = (const float*)d_in[7];
  const float* bv = (const float*)d_in[8];
  const float* wo = (const float*)d_in[9];
  const float* bo = (const float*)d_in[10];
  float* out = (float*)d_out;

  char* ws = (char*)d_ws;
  _Float16* Xh   = (_Float16*)(ws);                      // 0..32MB (reused q,k,v)
  _Float16* KT   = (_Float16*)(ws + 33554432);           // 32..64MB
  _Float16* VT   = (_Float16*)(ws + 67108864);           // 64..96MB
  _Float16* pKV  = (_Float16*)(ws + 100663296);          // 2.62MB over whk/whv
  _Float16* whk  = (_Float16*)(ws + 100663296);          // 2MB (dies after K-gemm)
  _Float16* whv  = (_Float16*)(ws + 102760448);          // 2MB (dies after V-gemm)
  _Float16* whq  = (_Float16*)(ws + 104857600);          // 2MB
  _Float16* who  = (_Float16*)(ws + 106954752);          // 2MB (lives to the end)
  _Float16* KVTx = (_Float16*)(ws + 109051904);          // 655KB
  _Float16* att  = KT;                                   // reuse KT after KV built

  const int N8_BIG = MROWS * KDIM / 8;             // 2,097,152
  const int GBLK   = (MROWS / 256) * (NDIM / 128); // 512 blocks (BK32)
  const int GBLK8  = (MROWS / 256) * (NDIM / 256); // 256 blocks (8-phase)

  // weights (fused small): 262,144 f4 -> (1024,4)
  cvt_w<<<dim3(1024, 4), 256, 0, stream>>>(wq, whq, wk, whk, wv, whv, wo, who);

  // K projection (8-phase challenger)
  cvt_f32_to_f16<<<2048, 256, 0, stream>>>(k, Xh, N8_BIG);
  gemm_8ph<1><<<GBLK8, 512, 0, stream>>>(Xh, whk, bk, KT);
  // V projection (8-phase challenger)
  cvt_f32_to_f16<<<2048, 256, 0, stream>>>(v, Xh, N8_BIG);
  gemm_8ph<0><<<GBLK8, 512, 0, stream>>>(Xh, whv, bv, VT);

  kv_mfma<<<dim3(64, 4), 256, 0, stream>>>(KT, VT, pKV);
  kv_combine<<<1280, 256, 0, stream>>>(pKV, KVTx);

  // Q projection + attention fused (BK32 champion)
  cvt_f32_to_f16<<<2048, 256, 0, stream>>>(q, Xh, N8_BIG);
  gemm_bk32<1, 0, 1, _Float16><<<GBLK, 512, 0, stream>>>(Xh, whq, bq, att, KVTx);

  // output projection -> d_out (BK32 champion)
  gemm_bk32<0, 0, 0, float><<<GBLK, 512, 0, stream>>>(att, who, bo, out, nullptr);
}

// Round 15
// 243.661 us; speedup vs baseline: 1.4413x; 1.0527x over previous
//
#include <hip/hip_runtime.h>
#include <hip/hip_bf16.h>

typedef _Float16 half8 __attribute__((ext_vector_type(8)));
typedef _Float16 half4 __attribute__((ext_vector_type(4)));
typedef float f32x4 __attribute__((ext_vector_type(4)));

#define KDIM 1024
#define NDIM 1024
#define MROWS 16384   // B*L = 4*4096

#define GLD_LDS16(g, l)                                                  \
  __builtin_amdgcn_global_load_lds(                                      \
      (const __attribute__((address_space(1))) void*)(g),                \
      (__attribute__((address_space(3))) void*)(l), 16, 0, 0)

// ---------------------------------------------------------------------------
// fp32 -> fp16 convert (r13 proven shape)
// ---------------------------------------------------------------------------
__global__ __launch_bounds__(256)
void cvt_f32_to_f16(const float* __restrict__ src, _Float16* __restrict__ dst,
                    int n8) {
  for (int i = blockIdx.x * 256 + threadIdx.x; i < n8; i += gridDim.x * 256) {
    float4 f0 = ((const float4*)src)[2 * i];
    float4 f1 = ((const float4*)src)[2 * i + 1];
    half8 h;
    h[0] = (_Float16)f0.x; h[1] = (_Float16)f0.y;
    h[2] = (_Float16)f0.z; h[3] = (_Float16)f0.w;
    h[4] = (_Float16)f1.x; h[5] = (_Float16)f1.y;
    h[6] = (_Float16)f1.z; h[7] = (_Float16)f1.w;
    ((half8*)dst)[i] = h;
  }
}

__global__ __launch_bounds__(256)
void cvt_w(const float* __restrict__ s0, _Float16* __restrict__ d0,
           const float* __restrict__ s1, _Float16* __restrict__ d1,
           const float* __restrict__ s2, _Float16* __restrict__ d2,
           const float* __restrict__ s3, _Float16* __restrict__ d3) {
  const float* src;
  _Float16* dst;
  switch (blockIdx.y) {
    case 0: src = s0; dst = d0; break;
    case 1: src = s1; dst = d1; break;
    case 2: src = s2; dst = d2; break;
    default: src = s3; dst = d3; break;
  }
  size_t i = (size_t)blockIdx.x * 256 + threadIdx.x;
  float4 f = ((const float4*)src)[i];
  half4 h;
  h[0] = (_Float16)f.x; h[1] = (_Float16)f.y;
  h[2] = (_Float16)f.z; h[3] = (_Float16)f.w;
  ((half4*)dst)[i] = h;
}

// ---------------------------------------------------------------------------
// 8-PHASE 256x256 GEMM (r14-verified main loop) — now used for ALL gemms.
// BM=BN=256, BK=64 as 2 K-halves of 32; 8 waves (2M x 4N; 128x64/wave).
// LDS = unified 128KB: As = smem[0:64K], Bs = smem[64K:128K];
// each operand [2 dbuf][2 kh][256 rows x 32 k].
// Per tile T (dbuf d=T&1): 4 phases; vmcnt(4)+barrier at p0/p2 only;
// stages write dbuf d^1; drain vmcnt(0) once at T=15 p2. Race-free ledger
// as verified in r14. Swizzle involution slot ^= (row>>1)&3 both sides.
// MODE: 0 = natural epilogue (bias+ACT, TOUT store)
//       1 = per-head transposed fp16 (K/V projections)
//       2 = fused linear-attention epilogue (Q proj + attn): Ct[256][256]
//           overlays smem (512B rows, byte ^= (row&7)<<4), block covers 4
//           heads (wave wn = head), KVTx B-frags direct from global,
//           two m-half passes (acc2[4][5] each), Z-scale, natural fp16 out.
// ---------------------------------------------------------------------------
template <int ACT, int MODE, typename TOUT>
__global__ __launch_bounds__(512, 2)
void gemm_8ph(const _Float16* __restrict__ X, const _Float16* __restrict__ W,
              const float* __restrict__ bias, TOUT* __restrict__ Y,
              const _Float16* __restrict__ KVTx) {
  __shared__ char smem[131072];
  _Float16* As = (_Float16*)smem;             // 64 KB
  _Float16* Bs = (_Float16*)(smem + 65536);   // 64 KB

  const int tid  = threadIdx.x;
  const int lane = tid & 63;
  const int w    = tid >> 6;        // 0..7
  const int wm   = w >> 2;          // 0..1 -> rows wm*128
  const int wn   = w & 3;           // 0..3 -> cols wn*64

  const int bid = blockIdx.x;
  const int wid = (bid & 7) * 32 + (bid >> 3);   // 256 blocks, bijective
  const int m0  = (wid >> 2) * 256;
  const int n0  = (wid & 3) * 256;

  const int srow = lane >> 2;
  const int gsl  = (lane & 3) ^ ((lane >> 3) & 3);
  const _Float16* gA = X + (size_t)(m0 + w * 32 + srow) * KDIM + gsl * 8;
  const _Float16* gB = W + (size_t)(n0 + w * 32 + srow) * KDIM + gsl * 8;

#define STG(OPD, GSRC, T, KH, D)                                             \
  {                                                                          \
    _Float16* ldst = OPD + ((D) * 2 + (KH)) * 8192 + (w * 32) * 32;          \
    const _Float16* gs = GSRC + (size_t)(T) * 64 + (KH) * 32;                \
    GLD_LDS16(gs, ldst);                                                     \
    GLD_LDS16(gs + (size_t)16 * KDIM, ldst + 16 * 32);                       \
  }

  const int rsl = ((lane >> 4) ^ ((lane >> 1) & 3)) << 4;

#define RDA(DST, D, KH, MH)                                                  \
  _Pragma("unroll") for (int mi = 0; mi < 4; ++mi) {                         \
    int r = wm * 128 + (MH) * 64 + mi * 16 + (lane & 15);                    \
    DST[mi] = *(const half8*)((const char*)As + ((D) * 2 + (KH)) * 16384 +   \
                              r * 64 + rsl);                                 \
  }
#define RDB(D, KH)                                                           \
  _Pragma("unroll") for (int ni = 0; ni < 4; ++ni) {                         \
    int r = wn * 64 + ni * 16 + (lane & 15);                                 \
    b[ni] = *(const half8*)((const char*)Bs + ((D) * 2 + (KH)) * 16384 +     \
                            r * 64 + rsl);                                   \
  }
#define MM(AV, MH)                                                           \
  __builtin_amdgcn_s_setprio(1);                                             \
  _Pragma("unroll") for (int mi = 0; mi < 4; ++mi)                           \
    _Pragma("unroll") for (int ni = 0; ni < 4; ++ni)                         \
      acc[(MH) * 4 + mi][ni] = __builtin_amdgcn_mfma_f32_16x16x32_f16(       \
          AV[mi], b[ni], acc[(MH) * 4 + mi][ni], 0, 0, 0);                   \
  __builtin_amdgcn_s_setprio(0);

  f32x4 acc[8][4] = {};
  half8 a0[4], a1[4], b[4];

  // prologue: tile 0 halves [A-kh0, B-kh0, A-kh1, B-kh1] -> dbuf 0
  STG(As, gA, 0, 0, 0); STG(Bs, gB, 0, 0, 0);
  STG(As, gA, 0, 1, 0); STG(Bs, gB, 0, 1, 0);

  for (int T = 0; T < 16; ++T) {
    const int d = T & 1, e = d ^ 1;
    // ---- p0: kh0, m-half0
    asm volatile("s_waitcnt vmcnt(4)" ::: "memory");
    asm volatile("s_barrier" ::: "memory");
    RDA(a0, d, 0, 0);
    RDB(d, 0);
    if (T < 15) STG(As, gA, T + 1, 0, e);
    MM(a0, 0);
    // ---- p1: kh0, m-half1
    RDA(a1, d, 0, 1);
    if (T < 15) STG(Bs, gB, T + 1, 0, e);
    MM(a1, 1);
    // ---- p2: kh1, m-half0
    if (T < 15) { asm volatile("s_waitcnt vmcnt(4)" ::: "memory"); }
    else        { asm volatile("s_waitcnt vmcnt(0)" ::: "memory"); }
    asm volatile("s_barrier" ::: "memory");
    RDA(a0, d, 1, 0);
    RDB(d, 1);
    if (T < 15) STG(As, gA, T + 1, 1, e);
    MM(a0, 0);
    // ---- p3: kh1, m-half1
    RDA(a1, d, 1, 1);
    if (T < 15) STG(Bs, gB, T + 1, 1, e);
    MM(a1, 1);
  }
#undef STG
#undef RDA
#undef RDB
#undef MM

  if constexpr (MODE == 2) {
    // ---- fused linear-attention epilogue -------------------------------
    __syncthreads();   // all waves done with staging LDS
    _Float16* Ct = (_Float16*)smem;   // [256 rows][256 cols], 512B rows
#pragma unroll
    for (int ni = 0; ni < 4; ++ni) {
      int cl   = wn * 64 + ni * 16 + (lane & 15);
      float bv = bias[n0 + cl];
#pragma unroll
      for (int mi = 0; mi < 8; ++mi) {
#pragma unroll
        for (int i = 0; i < 4; ++i) {
          int row = wm * 128 + mi * 16 + ((lane >> 4) << 2) + i;
          float v = acc[mi][ni][i] + bv;
          v = (v > 0.f) ? (v + 1.f) : __expf(v);
          int byte = row * 512 + cl * 2;
          byte ^= (row & 7) << 4;
          *(_Float16*)((char*)Ct + byte) = (_Float16)v;
        }
      }
    }
    __syncthreads();
    // wave's head: bh0 + wn; B-frags direct from KVTx (L2-hot)
    const int bh0 = ((m0 >> 12) << 4) + (n0 >> 6);
    const _Float16* kvp = KVTx + (size_t)(bh0 + wn) * 5120;
#pragma unroll
    for (int half = 0; half < 2; ++half) {
      f32x4 acc2[4][5] = {};
#pragma unroll
      for (int kk = 0; kk < 2; ++kk) {
        half8 afr2[4], bfr2[5];
#pragma unroll
        for (int m = 0; m < 4; ++m) {
          int row  = wm * 128 + half * 64 + m * 16 + (lane & 15);
          int byte = row * 512 + wn * 128 + kk * 64 + ((lane >> 4) << 4);
          byte ^= (row & 7) << 4;
          afr2[m] = *(const half8*)((const char*)Ct + byte);
        }
#pragma unroll
        for (int n = 0; n < 5; ++n) {
          int row = n * 16 + (lane & 15);
          bfr2[n] = *(const half8*)(kvp + row * 64 + kk * 32 + ((lane >> 4) << 3));
        }
#pragma unroll
        for (int m = 0; m < 4; ++m)
#pragma unroll
          for (int n = 0; n < 5; ++n)
            acc2[m][n] = __builtin_amdgcn_mfma_f32_16x16x32_f16(
                afr2[m], bfr2[n], acc2[m][n], 0, 0, 0);
      }
#pragma unroll
      for (int m = 0; m < 4; ++m) {
#pragma unroll
        for (int i = 0; i < 4; ++i) {
          float dn = __shfl(acc2[m][4][i], lane & 48);
          float z  = 1.f / (dn + 1e-6f);
          size_t row = (size_t)m0 + wm * 128 + half * 64 + m * 16 +
                       ((lane >> 4) << 2) + i;
#pragma unroll
          for (int n = 0; n < 4; ++n) {
            int col = n0 + wn * 64 + n * 16 + (lane & 15);
            Y[row * NDIM + col] = (TOUT)(acc2[m][n][i] * z);
          }
        }
      }
    }
    return;
  }

  // ---- MODE 0/1 epilogues
#pragma unroll
  for (int ni = 0; ni < 4; ++ni) {
    int col  = n0 + wn * 64 + ni * 16 + (lane & 15);
    float bv = bias[col];
#pragma unroll
    for (int mi = 0; mi < 8; ++mi) {
      int r0 = m0 + wm * 128 + mi * 16 + ((lane >> 4) << 2);
      if constexpr (MODE == 1) {
        int bb = r0 >> 12;
        int l0 = r0 & 4095;
        half4 hv;
#pragma unroll
        for (int i = 0; i < 4; ++i) {
          float v = acc[mi][ni][i] + bv;
          if constexpr (ACT == 1) v = (v > 0.f) ? (v + 1.f) : __expf(v);
          hv[i] = (_Float16)v;
        }
        *(half4*)((_Float16*)Y + ((size_t)(bb * 1024 + col)) * 4096 + l0) = hv;
      } else {
#pragma unroll
        for (int i = 0; i < 4; ++i) {
          float v = acc[mi][ni][i] + bv;
          if constexpr (ACT == 1) v = (v > 0.f) ? (v + 1.f) : __expf(v);
          Y[(size_t)(r0 + i) * NDIM + col] = (TOUT)v;
        }
      }
    }
  }
}

// ---------------------------------------------------------------------------
// kv_mfma: per (bh, chunk of 1024 l): partial C'[e][d] = sum_l VT[e][l]*KT[d][l]
// A = VT rows + synthesized ones-row (m-frag 4 -> Ksum); B = KT rows.
// ---------------------------------------------------------------------------
__global__ __launch_bounds__(256, 2)
void kv_mfma(const _Float16* __restrict__ KT, const _Float16* __restrict__ VT,
             _Float16* __restrict__ pKV) {
  const int bh = blockIdx.x;      // 0..63
  const int ch = blockIdx.y;      // 0..3
  const int tid  = threadIdx.x;
  const int lane = tid & 63;
  const int w    = tid >> 6;

  __shared__ _Float16 As[64 * 64];
  __shared__ _Float16 Bs[64 * 64];

  const int lr = lane >> 3;
  const int ls = (lane & 7) ^ lr;
  const size_t lbase = (size_t)ch * 1024 + ls * 8;
  const _Float16* gA = VT + (size_t)(bh * 64 + w * 16 + lr) * 4096 + lbase;
  const _Float16* gB = KT + (size_t)(bh * 64 + w * 16 + lr) * 4096 + lbase;
  _Float16* ldsA = As + (w * 16) * 64;
  _Float16* ldsB = Bs + (w * 16) * 64;

  half8 aones;
#pragma unroll
  for (int j = 0; j < 8; ++j) aones[j] = (lane & 15) == 0 ? (_Float16)1.0f : (_Float16)0.0f;

  f32x4 acc[5] = {};

  for (int k0 = 0; k0 < 1024; k0 += 64) {
    __syncthreads();
#pragma unroll
    for (int c = 0; c < 2; ++c) {
      GLD_LDS16(gA + k0 + (size_t)(c * 8) * 4096, ldsA + c * 8 * 64);
      GLD_LDS16(gB + k0 + (size_t)(c * 8) * 4096, ldsB + c * 8 * 64);
    }
    __syncthreads();

    half8 afr[4][2], bfr[2];
#pragma unroll
    for (int m = 0; m < 4; ++m)
#pragma unroll
      for (int kk = 0; kk < 2; ++kk) {
        int row  = m * 16 + (lane & 15);
        int byte = row * 128 + ((lane >> 4) << 4) + kk * 64;
        byte ^= (row & 7) << 4;
        afr[m][kk] = *(const half8*)((const char*)As + byte);
      }
#pragma unroll
    for (int kk = 0; kk < 2; ++kk) {
      int row  = w * 16 + (lane & 15);
      int byte = row * 128 + ((lane >> 4) << 4) + kk * 64;
      byte ^= (row & 7) << 4;
      bfr[kk] = *(const half8*)((const char*)Bs + byte);
    }
#pragma unroll
    for (int kk = 0; kk < 2; ++kk) {
#pragma unroll
      for (int m = 0; m < 4; ++m)
        acc[m] = __builtin_amdgcn_mfma_f32_16x16x32_f16(afr[m][kk], bfr[kk],
                                                        acc[m], 0, 0, 0);
      acc[4] = __builtin_amdgcn_mfma_f32_16x16x32_f16(aones, bfr[kk],
                                                      acc[4], 0, 0, 0);
    }
  }

  _Float16* outp = pKV + ((size_t)ch * 64 + bh) * 5120;
  const int col = w * 16 + (lane & 15);
#pragma unroll
  for (int m = 0; m < 5; ++m) {
#pragma unroll
    for (int i = 0; i < 4; ++i) {
      int row = m * 16 + ((lane >> 4) << 2) + i;
      outp[row * 64 + col] = (_Float16)acc[m][i];
    }
  }
}

// ---------------------------------------------------------------------------
__global__ __launch_bounds__(256)
void kv_combine(const _Float16* __restrict__ pKV, _Float16* __restrict__ KVTx) {
  int g = blockIdx.x * 256 + threadIdx.x;   // 0..327679
  int bh = g / 5120;
  int j  = g - bh * 5120;
  float s = 0.f;
#pragma unroll
  for (int ch = 0; ch < 4; ++ch)
    s += (float)pKV[((size_t)ch * 64 + bh) * 5120 + j];
  KVTx[(size_t)bh * 5120 + j] = (_Float16)s;
}

// ---------------------------------------------------------------------------
extern "C" void kernel_launch(void* const* d_in, const int* in_sizes, int n_in,
                              void* d_out, int out_size, void* d_ws, size_t ws_size,
                              hipStream_t stream) {
  const float* q  = (const float*)d_in[0];
  const float* k  = (const float*)d_in[1];
  const float* v  = (const float*)d_in[2];
  const float* wq = (const float*)d_in[3];
  const float* bq = (const float*)d_in[4];
  const float* wk = (const float*)d_in[5];
  const float* bk = (const float*)d_in[6];
  const float* wv = (const float*)d_in[7];
  const float* bv = (const float*)d_in[8];
  const float* wo = (const float*)d_in[9];
  const float* bo = (const float*)d_in[10];
  float* out = (float*)d_out;

  char* ws = (char*)d_ws;
  _Float16* Xh   = (_Float16*)(ws);                      // 0..32MB (reused q,k,v)
  _Float16* KT   = (_Float16*)(ws + 33554432);           // 32..64MB
  _Float16* VT   = (_Float16*)(ws + 67108864);           // 64..96MB
  _Float16* pKV  = (_Float16*)(ws + 100663296);          // 2.62MB over whk/whv
  _Float16* whk  = (_Float16*)(ws + 100663296);          // 2MB (dies after K-gemm)
  _Float16* whv  = (_Float16*)(ws + 102760448);          // 2MB (dies after V-gemm)
  _Float16* whq  = (_Float16*)(ws + 104857600);          // 2MB
  _Float16* who  = (_Float16*)(ws + 106954752);          // 2MB (lives to the end)
  _Float16* KVTx = (_Float16*)(ws + 109051904);          // 655KB
  _Float16* att  = KT;                                   // reuse KT after KV built

  const int N8_BIG = MROWS * KDIM / 8;             // 2,097,152
  const int GBLK8  = (MROWS / 256) * (NDIM / 256); // 256 blocks

  // weights (fused small): 262,144 f4 -> (1024,4)
  cvt_w<<<dim3(1024, 4), 256, 0, stream>>>(wq, whq, wk, whk, wv, whv, wo, who);

  // K projection (8-phase, per-head transposed)
  cvt_f32_to_f16<<<2048, 256, 0, stream>>>(k, Xh, N8_BIG);
  gemm_8ph<1, 1, _Float16><<<GBLK8, 512, 0, stream>>>(Xh, whk, bk, KT, nullptr);
  // V projection
  cvt_f32_to_f16<<<2048, 256, 0, stream>>>(v, Xh, N8_BIG);
  gemm_8ph<0, 1, _Float16><<<GBLK8, 512, 0, stream>>>(Xh, whv, bv, VT, nullptr);

  kv_mfma<<<dim3(64, 4), 256, 0, stream>>>(KT, VT, pKV);
  kv_combine<<<1280, 256, 0, stream>>>(pKV, KVTx);

  // Q projection + attention fused (8-phase main loop + 4-head epilogue)
  cvt_f32_to_f16<<<2048, 256, 0, stream>>>(q, Xh, N8_BIG);
  gemm_8ph<1, 2, _Float16><<<GBLK8, 512, 0, stream>>>(Xh, whq, bq, att, KVTx);

  // output projection (8-phase, natural fp32) -> d_out
  gemm_8ph<0, 0, float><<<GBLK8, 512, 0, stream>>>(att, who, bo, out, nullptr);
}

// Round 16
// 242.238 us; speedup vs baseline: 1.4498x; 1.0059x over previous
//
#include <hip/hip_runtime.h>
#include <hip/hip_bf16.h>

typedef _Float16 half8 __attribute__((ext_vector_type(8)));
typedef _Float16 half4 __attribute__((ext_vector_type(4)));
typedef float f32x4 __attribute__((ext_vector_type(4)));

#define KDIM 1024
#define NDIM 1024
#define MROWS 16384   // B*L = 4*4096

#define GLD_LDS16(g, l)                                                  \
  __builtin_amdgcn_global_load_lds(                                      \
      (const __attribute__((address_space(1))) void*)(g),                \
      (__attribute__((address_space(3))) void*)(l), 16, 0, 0)

// ---------------------------------------------------------------------------
// fp32 -> fp16 convert (r13 shape, 4096 blocks for TLP)
// ---------------------------------------------------------------------------
__global__ __launch_bounds__(256)
void cvt_f32_to_f16(const float* __restrict__ src, _Float16* __restrict__ dst,
                    int n8) {
  for (int i = blockIdx.x * 256 + threadIdx.x; i < n8; i += gridDim.x * 256) {
    float4 f0 = ((const float4*)src)[2 * i];
    float4 f1 = ((const float4*)src)[2 * i + 1];
    half8 h;
    h[0] = (_Float16)f0.x; h[1] = (_Float16)f0.y;
    h[2] = (_Float16)f0.z; h[3] = (_Float16)f0.w;
    h[4] = (_Float16)f1.x; h[5] = (_Float16)f1.y;
    h[6] = (_Float16)f1.z; h[7] = (_Float16)f1.w;
    ((half8*)dst)[i] = h;
  }
}

__global__ __launch_bounds__(256)
void cvt_w(const float* __restrict__ s0, _Float16* __restrict__ d0,
           const float* __restrict__ s1, _Float16* __restrict__ d1,
           const float* __restrict__ s2, _Float16* __restrict__ d2,
           const float* __restrict__ s3, _Float16* __restrict__ d3) {
  const float* src;
  _Float16* dst;
  switch (blockIdx.y) {
    case 0: src = s0; dst = d0; break;
    case 1: src = s1; dst = d1; break;
    case 2: src = s2; dst = d2; break;
    default: src = s3; dst = d3; break;
  }
  size_t i = (size_t)blockIdx.x * 256 + threadIdx.x;
  float4 f = ((const float4*)src)[i];
  half4 h;
  h[0] = (_Float16)f.x; h[1] = (_Float16)f.y;
  h[2] = (_Float16)f.z; h[3] = (_Float16)f.w;
  ((half4*)dst)[i] = h;
}

// ---------------------------------------------------------------------------
// 8-PHASE 256x256 GEMM (r14/r15-verified main loop).
// MODE: 0 natural, 1 per-head transposed fp16, 2 fused attn epilogue.
// MODE=2 v2 (r16): Ct is PER-WAVE-PRIVATE 16KB [128 rows][64 cols]
// (128B rows, (row&7)<<4 swizzle — kv_mfma-proven pattern). The attn
// sub-GEMM is wave-local (wave's 128 rows x its head's 64 d), so the
// second __syncthreads is replaced by wave-local lgkmcnt(0)+sched_barrier.
// ---------------------------------------------------------------------------
template <int ACT, int MODE, typename TOUT>
__global__ __launch_bounds__(512, 2)
void gemm_8ph(const _Float16* __restrict__ X, const _Float16* __restrict__ W,
              const float* __restrict__ bias, TOUT* __restrict__ Y,
              const _Float16* __restrict__ KVTx) {
  __shared__ char smem[131072];
  _Float16* As = (_Float16*)smem;             // 64 KB
  _Float16* Bs = (_Float16*)(smem + 65536);   // 64 KB

  const int tid  = threadIdx.x;
  const int lane = tid & 63;
  const int w    = tid >> 6;        // 0..7
  const int wm   = w >> 2;          // 0..1 -> rows wm*128
  const int wn   = w & 3;           // 0..3 -> cols wn*64

  const int bid = blockIdx.x;
  const int wid = (bid & 7) * 32 + (bid >> 3);   // 256 blocks, bijective
  const int m0  = (wid >> 2) * 256;
  const int n0  = (wid & 3) * 256;

  const int srow = lane >> 2;
  const int gsl  = (lane & 3) ^ ((lane >> 3) & 3);
  const _Float16* gA = X + (size_t)(m0 + w * 32 + srow) * KDIM + gsl * 8;
  const _Float16* gB = W + (size_t)(n0 + w * 32 + srow) * KDIM + gsl * 8;

#define STG(OPD, GSRC, T, KH, D)                                             \
  {                                                                          \
    _Float16* ldst = OPD + ((D) * 2 + (KH)) * 8192 + (w * 32) * 32;          \
    const _Float16* gs = GSRC + (size_t)(T) * 64 + (KH) * 32;                \
    GLD_LDS16(gs, ldst);                                                     \
    GLD_LDS16(gs + (size_t)16 * KDIM, ldst + 16 * 32);                       \
  }

  const int rsl = ((lane >> 4) ^ ((lane >> 1) & 3)) << 4;

#define RDA(DST, D, KH, MH)                                                  \
  _Pragma("unroll") for (int mi = 0; mi < 4; ++mi) {                         \
    int r = wm * 128 + (MH) * 64 + mi * 16 + (lane & 15);                    \
    DST[mi] = *(const half8*)((const char*)As + ((D) * 2 + (KH)) * 16384 +   \
                              r * 64 + rsl);                                 \
  }
#define RDB(D, KH)                                                           \
  _Pragma("unroll") for (int ni = 0; ni < 4; ++ni) {                         \
    int r = wn * 64 + ni * 16 + (lane & 15);                                 \
    b[ni] = *(const half8*)((const char*)Bs + ((D) * 2 + (KH)) * 16384 +     \
                            r * 64 + rsl);                                   \
  }
#define MM(AV, MH)                                                           \
  __builtin_amdgcn_s_setprio(1);                                             \
  _Pragma("unroll") for (int mi = 0; mi < 4; ++mi)                           \
    _Pragma("unroll") for (int ni = 0; ni < 4; ++ni)                         \
      acc[(MH) * 4 + mi][ni] = __builtin_amdgcn_mfma_f32_16x16x32_f16(       \
          AV[mi], b[ni], acc[(MH) * 4 + mi][ni], 0, 0, 0);                   \
  __builtin_amdgcn_s_setprio(0);

  f32x4 acc[8][4] = {};
  half8 a0[4], a1[4], b[4];

  // prologue: tile 0 halves [A-kh0, B-kh0, A-kh1, B-kh1] -> dbuf 0
  STG(As, gA, 0, 0, 0); STG(Bs, gB, 0, 0, 0);
  STG(As, gA, 0, 1, 0); STG(Bs, gB, 0, 1, 0);

  for (int T = 0; T < 16; ++T) {
    const int d = T & 1, e = d ^ 1;
    // ---- p0: kh0, m-half0
    asm volatile("s_waitcnt vmcnt(4)" ::: "memory");
    asm volatile("s_barrier" ::: "memory");
    RDA(a0, d, 0, 0);
    RDB(d, 0);
    if (T < 15) STG(As, gA, T + 1, 0, e);
    MM(a0, 0);
    // ---- p1: kh0, m-half1
    RDA(a1, d, 0, 1);
    if (T < 15) STG(Bs, gB, T + 1, 0, e);
    MM(a1, 1);
    // ---- p2: kh1, m-half0
    if (T < 15) { asm volatile("s_waitcnt vmcnt(4)" ::: "memory"); }
    else        { asm volatile("s_waitcnt vmcnt(0)" ::: "memory"); }
    asm volatile("s_barrier" ::: "memory");
    RDA(a0, d, 1, 0);
    RDB(d, 1);
    if (T < 15) STG(As, gA, T + 1, 1, e);
    MM(a0, 0);
    // ---- p3: kh1, m-half1
    RDA(a1, d, 1, 1);
    if (T < 15) STG(Bs, gB, T + 1, 1, e);
    MM(a1, 1);
  }
#undef STG
#undef RDA
#undef RDB
#undef MM

  if constexpr (MODE == 2) {
    // ---- fused linear-attention epilogue (per-wave-private Ct) ----------
    __syncthreads();   // all waves done reading staging LDS
    _Float16* Cw = (_Float16*)(smem + w * 16384);   // wave-private 16KB
    // write Q = elu(acc+bias)+1, layout [128 rows][64 cols], 128B rows,
    // swizzle byte ^= (row&7)<<4 (kv_mfma-proven)
#pragma unroll
    for (int ni = 0; ni < 4; ++ni) {
      int dcol = ni * 16 + (lane & 15);          // d within head, 0..63
      float bv = bias[n0 + wn * 64 + dcol];
#pragma unroll
      for (int mi = 0; mi < 8; ++mi) {
#pragma unroll
        for (int i = 0; i < 4; ++i) {
          int rowr = mi * 16 + ((lane >> 4) << 2) + i;   // 0..127
          float v = acc[mi][ni][i] + bv;
          v = (v > 0.f) ? (v + 1.f) : __expf(v);
          int byte = rowr * 128 + dcol * 2;
          byte ^= (rowr & 7) << 4;
          *(_Float16*)((char*)Cw + byte) = (_Float16)v;
        }
      }
    }
    // wave-local RAW fence: all ds_writes done before ds_reads (rule-18)
    asm volatile("s_waitcnt lgkmcnt(0)" ::: "memory");
    __builtin_amdgcn_sched_barrier(0);
    // attn sub-GEMM: A = Cw rows, B = KVTx head panel (global, L2-hot)
    const int bh0 = ((m0 >> 12) << 4) + (n0 >> 6);
    const _Float16* kvp = KVTx + (size_t)(bh0 + wn) * 5120;
#pragma unroll
    for (int half = 0; half < 2; ++half) {
      f32x4 acc2[4][5] = {};
#pragma unroll
      for (int kk = 0; kk < 2; ++kk) {
        half8 afr2[4], bfr2[5];
#pragma unroll
        for (int m = 0; m < 4; ++m) {
          int rowr = half * 64 + m * 16 + (lane & 15);
          int byte = rowr * 128 + kk * 64 + ((lane >> 4) << 4);
          byte ^= (rowr & 7) << 4;
          afr2[m] = *(const half8*)((const char*)Cw + byte);
        }
#pragma unroll
        for (int n = 0; n < 5; ++n) {
          int row = n * 16 + (lane & 15);
          bfr2[n] = *(const half8*)(kvp + row * 64 + kk * 32 + ((lane >> 4) << 3));
        }
#pragma unroll
        for (int m = 0; m < 4; ++m)
#pragma unroll
          for (int n = 0; n < 5; ++n)
            acc2[m][n] = __builtin_amdgcn_mfma_f32_16x16x32_f16(
                afr2[m], bfr2[n], acc2[m][n], 0, 0, 0);
      }
#pragma unroll
      for (int m = 0; m < 4; ++m) {
#pragma unroll
        for (int i = 0; i < 4; ++i) {
          float dn = __shfl(acc2[m][4][i], lane & 48);
          float z  = 1.f / (dn + 1e-6f);
          size_t row = (size_t)m0 + wm * 128 + half * 64 + m * 16 +
                       ((lane >> 4) << 2) + i;
#pragma unroll
          for (int n = 0; n < 4; ++n) {
            int col = n0 + wn * 64 + n * 16 + (lane & 15);
            Y[row * NDIM + col] = (TOUT)(acc2[m][n][i] * z);
          }
        }
      }
    }
    return;
  }

  // ---- MODE 0/1 epilogues
#pragma unroll
  for (int ni = 0; ni < 4; ++ni) {
    int col  = n0 + wn * 64 + ni * 16 + (lane & 15);
    float bv = bias[col];
#pragma unroll
    for (int mi = 0; mi < 8; ++mi) {
      int r0 = m0 + wm * 128 + mi * 16 + ((lane >> 4) << 2);
      if constexpr (MODE == 1) {
        int bb = r0 >> 12;
        int l0 = r0 & 4095;
        half4 hv;
#pragma unroll
        for (int i = 0; i < 4; ++i) {
          float v = acc[mi][ni][i] + bv;
          if constexpr (ACT == 1) v = (v > 0.f) ? (v + 1.f) : __expf(v);
          hv[i] = (_Float16)v;
        }
        *(half4*)((_Float16*)Y + ((size_t)(bb * 1024 + col)) * 4096 + l0) = hv;
      } else {
#pragma unroll
        for (int i = 0; i < 4; ++i) {
          float v = acc[mi][ni][i] + bv;
          if constexpr (ACT == 1) v = (v > 0.f) ? (v + 1.f) : __expf(v);
          Y[(size_t)(r0 + i) * NDIM + col] = (TOUT)v;
        }
      }
    }
  }
}

// ---------------------------------------------------------------------------
// kv_mfma: per (bh, chunk of 1024 l): partial C'[e][d] = sum_l VT[e][l]*KT[d][l]
// A = VT rows + synthesized ones-row (m-frag 4 -> Ksum); B = KT rows.
// ---------------------------------------------------------------------------
__global__ __launch_bounds__(256, 2)
void kv_mfma(const _Float16* __restrict__ KT, const _Float16* __restrict__ VT,
             _Float16* __restrict__ pKV) {
  const int bh = blockIdx.x;      // 0..63
  const int ch = blockIdx.y;      // 0..3
  const int tid  = threadIdx.x;
  const int lane = tid & 63;
  const int w    = tid >> 6;

  __shared__ _Float16 As[64 * 64];
  __shared__ _Float16 Bs[64 * 64];

  const int lr = lane >> 3;
  const int ls = (lane & 7) ^ lr;
  const size_t lbase = (size_t)ch * 1024 + ls * 8;
  const _Float16* gA = VT + (size_t)(bh * 64 + w * 16 + lr) * 4096 + lbase;
  const _Float16* gB = KT + (size_t)(bh * 64 + w * 16 + lr) * 4096 + lbase;
  _Float16* ldsA = As + (w * 16) * 64;
  _Float16* ldsB = Bs + (w * 16) * 64;

  half8 aones;
#pragma unroll
  for (int j = 0; j < 8; ++j) aones[j] = (lane & 15) == 0 ? (_Float16)1.0f : (_Float16)0.0f;

  f32x4 acc[5] = {};

  for (int k0 = 0; k0 < 1024; k0 += 64) {
    __syncthreads();
#pragma unroll
    for (int c = 0; c < 2; ++c) {
      GLD_LDS16(gA + k0 + (size_t)(c * 8) * 4096, ldsA + c * 8 * 64);
      GLD_LDS16(gB + k0 + (size_t)(c * 8) * 4096, ldsB + c * 8 * 64);
    }
    __syncthreads();

    half8 afr[4][2], bfr[2];
#pragma unroll
    for (int m = 0; m < 4; ++m)
#pragma unroll
      for (int kk = 0; kk < 2; ++kk) {
        int row  = m * 16 + (lane & 15);
        int byte = row * 128 + ((lane >> 4) << 4) + kk * 64;
        byte ^= (row & 7) << 4;
        afr[m][kk] = *(const half8*)((const char*)As + byte);
      }
#pragma unroll
    for (int kk = 0; kk < 2; ++kk) {
      int row  = w * 16 + (lane & 15);
      int byte = row * 128 + ((lane >> 4) << 4) + kk * 64;
      byte ^= (row & 7) << 4;
      bfr[kk] = *(const half8*)((const char*)Bs + byte);
    }
#pragma unroll
    for (int kk = 0; kk < 2; ++kk) {
#pragma unroll
      for (int m = 0; m < 4; ++m)
        acc[m] = __builtin_amdgcn_mfma_f32_16x16x32_f16(afr[m][kk], bfr[kk],
                                                        acc[m], 0, 0, 0);
      acc[4] = __builtin_amdgcn_mfma_f32_16x16x32_f16(aones, bfr[kk],
                                                      acc[4], 0, 0, 0);
    }
  }

  _Float16* outp = pKV + ((size_t)ch * 64 + bh) * 5120;
  const int col = w * 16 + (lane & 15);
#pragma unroll
  for (int m = 0; m < 5; ++m) {
#pragma unroll
    for (int i = 0; i < 4; ++i) {
      int row = m * 16 + ((lane >> 4) << 2) + i;
      outp[row * 64 + col] = (_Float16)acc[m][i];
    }
  }
}

// ---------------------------------------------------------------------------
__global__ __launch_bounds__(256)
void kv_combine(const _Float16* __restrict__ pKV, _Float16* __restrict__ KVTx) {
  int g = blockIdx.x * 256 + threadIdx.x;   // 0..327679
  int bh = g / 5120;
  int j  = g - bh * 5120;
  float s = 0.f;
#pragma unroll
  for (int ch = 0; ch < 4; ++ch)
    s += (float)pKV[((size_t)ch * 64 + bh) * 5120 + j];
  KVTx[(size_t)bh * 5120 + j] = (_Float16)s;
}

// ---------------------------------------------------------------------------
extern "C" void kernel_launch(void* const* d_in, const int* in_sizes, int n_in,
                              void* d_out, int out_size, void* d_ws, size_t ws_size,
                              hipStream_t stream) {
  const float* q  = (const float*)d_in[0];
  const float* k  = (const float*)d_in[1];
  const float* v  = (const float*)d_in[2];
  const float* wq = (const float*)d_in[3];
  const float* bq = (const float*)d_in[4];
  const float* wk = (const float*)d_in[5];
  const float* bk = (const float*)d_in[6];
  const float* wv = (const float*)d_in[7];
  const float* bv = (const float*)d_in[8];
  const float* wo = (const float*)d_in[9];
  const float* bo = (const float*)d_in[10];
  float* out = (float*)d_out;

  char* ws = (char*)d_ws;
  _Float16* Xh   = (_Float16*)(ws);                      // 0..32MB (reused q,k,v)
  _Float16* KT   = (_Float16*)(ws + 33554432);           // 32..64MB
  _Float16* VT   = (_Float16*)(ws + 67108864);           // 64..96MB
  _Float16* pKV  = (_Float16*)(ws + 100663296);          // 2.62MB over whk/whv
  _Float16* whk  = (_Float16*)(ws + 100663296);          // 2MB (dies after K-gemm)
  _Float16* whv  = (_Float16*)(ws + 102760448);          // 2MB (dies after V-gemm)
  _Float16* whq  = (_Float16*)(ws + 104857600);          // 2MB
  _Float16* who  = (_Float16*)(ws + 106954752);          // 2MB (lives to the end)
  _Float16* KVTx = (_Float16*)(ws + 109051904);          // 655KB
  _Float16* att  = KT;                                   // reuse KT after KV built

  const int N8_BIG = MROWS * KDIM / 8;             // 2,097,152
  const int GBLK8  = (MROWS / 256) * (NDIM / 256); // 256 blocks

  // weights (fused small): 262,144 f4 -> (1024,4)
  cvt_w<<<dim3(1024, 4), 256, 0, stream>>>(wq, whq, wk, whk, wv, whv, wo, who);

  // K projection (8-phase, per-head transposed)
  cvt_f32_to_f16<<<4096, 256, 0, stream>>>(k, Xh, N8_BIG);
  gemm_8ph<1, 1, _Float16><<<GBLK8, 512, 0, stream>>>(Xh, whk, bk, KT, nullptr);
  // V projection
  cvt_f32_to_f16<<<4096, 256, 0, stream>>>(v, Xh, N8_BIG);
  gemm_8ph<0, 1, _Float16><<<GBLK8, 512, 0, stream>>>(Xh, whv, bv, VT, nullptr);

  kv_mfma<<<dim3(64, 4), 256, 0, stream>>>(KT, VT, pKV);
  kv_combine<<<1280, 256, 0, stream>>>(pKV, KVTx);

  // Q projection + attention fused (8-phase + per-wave Ct epilogue)
  cvt_f32_to_f16<<<4096, 256, 0, stream>>>(q, Xh, N8_BIG);
  gemm_8ph<1, 2, _Float16><<<GBLK8, 512, 0, stream>>>(Xh, whq, bq, att, KVTx);

  // output projection (8-phase, natural fp32) -> d_out
  gemm_8ph<0, 0, float><<<GBLK8, 512, 0, stream>>>(att, who, bo, out, nullptr);
}

// Round 17
// 238.102 us; speedup vs baseline: 1.4750x; 1.0174x over previous
//
#include <hip/hip_runtime.h>
#include <hip/hip_bf16.h>

typedef _Float16 half8 __attribute__((ext_vector_type(8)));
typedef _Float16 half4 __attribute__((ext_vector_type(4)));
typedef float f32x4 __attribute__((ext_vector_type(4)));

#define KDIM 1024
#define NDIM 1024
#define MROWS 16384   // B*L = 4*4096

#define GLD_LDS16(g, l)                                                  \
  __builtin_amdgcn_global_load_lds(                                      \
      (const __attribute__((address_space(1))) void*)(g),                \
      (__attribute__((address_space(3))) void*)(l), 16, 0, 0)

// ---------------------------------------------------------------------------
// fp32 -> fp16 convert (standalone, only for k now)
// ---------------------------------------------------------------------------
__global__ __launch_bounds__(256)
void cvt_f32_to_f16(const float* __restrict__ src, _Float16* __restrict__ dst,
                    int n8) {
  for (int i = blockIdx.x * 256 + threadIdx.x; i < n8; i += gridDim.x * 256) {
    float4 f0 = ((const float4*)src)[2 * i];
    float4 f1 = ((const float4*)src)[2 * i + 1];
    half8 h;
    h[0] = (_Float16)f0.x; h[1] = (_Float16)f0.y;
    h[2] = (_Float16)f0.z; h[3] = (_Float16)f0.w;
    h[4] = (_Float16)f1.x; h[5] = (_Float16)f1.y;
    h[6] = (_Float16)f1.z; h[7] = (_Float16)f1.w;
    ((half8*)dst)[i] = h;
  }
}

__global__ __launch_bounds__(256)
void cvt_w(const float* __restrict__ s0, _Float16* __restrict__ d0,
           const float* __restrict__ s1, _Float16* __restrict__ d1,
           const float* __restrict__ s2, _Float16* __restrict__ d2,
           const float* __restrict__ s3, _Float16* __restrict__ d3) {
  const float* src;
  _Float16* dst;
  switch (blockIdx.y) {
    case 0: src = s0; dst = d0; break;
    case 1: src = s1; dst = d1; break;
    case 2: src = s2; dst = d2; break;
    default: src = s3; dst = d3; break;
  }
  size_t i = (size_t)blockIdx.x * 256 + threadIdx.x;
  float4 f = ((const float4*)src)[i];
  half4 h;
  h[0] = (_Float16)f.x; h[1] = (_Float16)f.y;
  h[2] = (_Float16)f.z; h[3] = (_Float16)f.w;
  ((half4*)dst)[i] = h;
}

// ---------------------------------------------------------------------------
// 8-PHASE 256x256 GEMM (r14/r15/r16-verified main loop).
// MODE: 0 natural, 1 per-head transposed fp16, 2 fused attn epilogue
//       (per-wave-private Ct, r16-verified: bank conflicts = 0).
// CVT (r17): 1 = grid-stride fp32->fp16 convert TAIL (csrc -> cdst, full
// 16M elems across the 256-block grid). Runs after the epilogue; while some
// blocks are still in MFMA phases, finished blocks stream the convert —
// overlapping the BW-bound cvt with the latency-bound GEMM instead of
// serializing them as separate dispatches. Output consumed only by the
// NEXT dispatch (stream order) -> race-free.
// ---------------------------------------------------------------------------
template <int ACT, int MODE, int CVT, typename TOUT>
__global__ __launch_bounds__(512, 2)
void gemm_8ph(const _Float16* __restrict__ X, const _Float16* __restrict__ W,
              const float* __restrict__ bias, TOUT* __restrict__ Y,
              const _Float16* __restrict__ KVTx,
              const float* __restrict__ csrc, _Float16* __restrict__ cdst) {
  __shared__ char smem[131072];
  _Float16* As = (_Float16*)smem;             // 64 KB
  _Float16* Bs = (_Float16*)(smem + 65536);   // 64 KB

  const int tid  = threadIdx.x;
  const int lane = tid & 63;
  const int w    = tid >> 6;        // 0..7
  const int wm   = w >> 2;          // 0..1 -> rows wm*128
  const int wn   = w & 3;           // 0..3 -> cols wn*64

  const int bid = blockIdx.x;
  const int wid = (bid & 7) * 32 + (bid >> 3);   // 256 blocks, bijective
  const int m0  = (wid >> 2) * 256;
  const int n0  = (wid & 3) * 256;

  const int srow = lane >> 2;
  const int gsl  = (lane & 3) ^ ((lane >> 3) & 3);
  const _Float16* gA = X + (size_t)(m0 + w * 32 + srow) * KDIM + gsl * 8;
  const _Float16* gB = W + (size_t)(n0 + w * 32 + srow) * KDIM + gsl * 8;

#define STG(OPD, GSRC, T, KH, D)                                             \
  {                                                                          \
    _Float16* ldst = OPD + ((D) * 2 + (KH)) * 8192 + (w * 32) * 32;          \
    const _Float16* gs = GSRC + (size_t)(T) * 64 + (KH) * 32;                \
    GLD_LDS16(gs, ldst);                                                     \
    GLD_LDS16(gs + (size_t)16 * KDIM, ldst + 16 * 32);                       \
  }

  const int rsl = ((lane >> 4) ^ ((lane >> 1) & 3)) << 4;

#define RDA(DST, D, KH, MH)                                                  \
  _Pragma("unroll") for (int mi = 0; mi < 4; ++mi) {                         \
    int r = wm * 128 + (MH) * 64 + mi * 16 + (lane & 15);                    \
    DST[mi] = *(const half8*)((const char*)As + ((D) * 2 + (KH)) * 16384 +   \
                              r * 64 + rsl);                                 \
  }
#define RDB(D, KH)                                                           \
  _Pragma("unroll") for (int ni = 0; ni < 4; ++ni) {                         \
    int r = wn * 64 + ni * 16 + (lane & 15);                                 \
    b[ni] = *(const half8*)((const char*)Bs + ((D) * 2 + (KH)) * 16384 +     \
                            r * 64 + rsl);                                   \
  }
#define MM(AV, MH)                                                           \
  __builtin_amdgcn_s_setprio(1);                                             \
  _Pragma("unroll") for (int mi = 0; mi < 4; ++mi)                           \
    _Pragma("unroll") for (int ni = 0; ni < 4; ++ni)                         \
      acc[(MH) * 4 + mi][ni] = __builtin_amdgcn_mfma_f32_16x16x32_f16(       \
          AV[mi], b[ni], acc[(MH) * 4 + mi][ni], 0, 0, 0);                   \
  __builtin_amdgcn_s_setprio(0);

  f32x4 acc[8][4] = {};
  half8 a0[4], a1[4], b[4];

  // prologue: tile 0 halves [A-kh0, B-kh0, A-kh1, B-kh1] -> dbuf 0
  STG(As, gA, 0, 0, 0); STG(Bs, gB, 0, 0, 0);
  STG(As, gA, 0, 1, 0); STG(Bs, gB, 0, 1, 0);

  for (int T = 0; T < 16; ++T) {
    const int d = T & 1, e = d ^ 1;
    // ---- p0: kh0, m-half0
    asm volatile("s_waitcnt vmcnt(4)" ::: "memory");
    asm volatile("s_barrier" ::: "memory");
    RDA(a0, d, 0, 0);
    RDB(d, 0);
    if (T < 15) STG(As, gA, T + 1, 0, e);
    MM(a0, 0);
    // ---- p1: kh0, m-half1
    RDA(a1, d, 0, 1);
    if (T < 15) STG(Bs, gB, T + 1, 0, e);
    MM(a1, 1);
    // ---- p2: kh1, m-half0
    if (T < 15) { asm volatile("s_waitcnt vmcnt(4)" ::: "memory"); }
    else        { asm volatile("s_waitcnt vmcnt(0)" ::: "memory"); }
    asm volatile("s_barrier" ::: "memory");
    RDA(a0, d, 1, 0);
    RDB(d, 1);
    if (T < 15) STG(As, gA, T + 1, 1, e);
    MM(a0, 0);
    // ---- p3: kh1, m-half1
    RDA(a1, d, 1, 1);
    if (T < 15) STG(Bs, gB, T + 1, 1, e);
    MM(a1, 1);
  }
#undef STG
#undef RDA
#undef RDB
#undef MM

  if constexpr (MODE == 2) {
    // ---- fused linear-attention epilogue (per-wave-private Ct, r16) -----
    __syncthreads();   // all waves done reading staging LDS
    _Float16* Cw = (_Float16*)(smem + w * 16384);   // wave-private 16KB
#pragma unroll
    for (int ni = 0; ni < 4; ++ni) {
      int dcol = ni * 16 + (lane & 15);          // d within head, 0..63
      float bv = bias[n0 + wn * 64 + dcol];
#pragma unroll
      for (int mi = 0; mi < 8; ++mi) {
#pragma unroll
        for (int i = 0; i < 4; ++i) {
          int rowr = mi * 16 + ((lane >> 4) << 2) + i;   // 0..127
          float v = acc[mi][ni][i] + bv;
          v = (v > 0.f) ? (v + 1.f) : __expf(v);
          int byte = rowr * 128 + dcol * 2;
          byte ^= (rowr & 7) << 4;
          *(_Float16*)((char*)Cw + byte) = (_Float16)v;
        }
      }
    }
    asm volatile("s_waitcnt lgkmcnt(0)" ::: "memory");
    __builtin_amdgcn_sched_barrier(0);
    const int bh0 = ((m0 >> 12) << 4) + (n0 >> 6);
    const _Float16* kvp = KVTx + (size_t)(bh0 + wn) * 5120;
#pragma unroll
    for (int half = 0; half < 2; ++half) {
      f32x4 acc2[4][5] = {};
#pragma unroll
      for (int kk = 0; kk < 2; ++kk) {
        half8 afr2[4], bfr2[5];
#pragma unroll
        for (int m = 0; m < 4; ++m) {
          int rowr = half * 64 + m * 16 + (lane & 15);
          int byte = rowr * 128 + kk * 64 + ((lane >> 4) << 4);
          byte ^= (rowr & 7) << 4;
          afr2[m] = *(const half8*)((const char*)Cw + byte);
        }
#pragma unroll
        for (int n = 0; n < 5; ++n) {
          int row = n * 16 + (lane & 15);
          bfr2[n] = *(const half8*)(kvp + row * 64 + kk * 32 + ((lane >> 4) << 3));
        }
#pragma unroll
        for (int m = 0; m < 4; ++m)
#pragma unroll
          for (int n = 0; n < 5; ++n)
            acc2[m][n] = __builtin_amdgcn_mfma_f32_16x16x32_f16(
                afr2[m], bfr2[n], acc2[m][n], 0, 0, 0);
      }
#pragma unroll
      for (int m = 0; m < 4; ++m) {
#pragma unroll
        for (int i = 0; i < 4; ++i) {
          float dn = __shfl(acc2[m][4][i], lane & 48);
          float z  = 1.f / (dn + 1e-6f);
          size_t row = (size_t)m0 + wm * 128 + half * 64 + m * 16 +
                       ((lane >> 4) << 2) + i;
#pragma unroll
          for (int n = 0; n < 4; ++n) {
            int col = n0 + wn * 64 + n * 16 + (lane & 15);
            Y[row * NDIM + col] = (TOUT)(acc2[m][n][i] * z);
          }
        }
      }
    }
    return;
  }

  // ---- MODE 0/1 epilogues
#pragma unroll
  for (int ni = 0; ni < 4; ++ni) {
    int col  = n0 + wn * 64 + ni * 16 + (lane & 15);
    float bv = bias[col];
#pragma unroll
    for (int mi = 0; mi < 8; ++mi) {
      int r0 = m0 + wm * 128 + mi * 16 + ((lane >> 4) << 2);
      if constexpr (MODE == 1) {
        int bb = r0 >> 12;
        int l0 = r0 & 4095;
        half4 hv;
#pragma unroll
        for (int i = 0; i < 4; ++i) {
          float v = acc[mi][ni][i] + bv;
          if constexpr (ACT == 1) v = (v > 0.f) ? (v + 1.f) : __expf(v);
          hv[i] = (_Float16)v;
        }
        *(half4*)((_Float16*)Y + ((size_t)(bb * 1024 + col)) * 4096 + l0) = hv;
      } else {
#pragma unroll
        for (int i = 0; i < 4; ++i) {
          float v = acc[mi][ni][i] + bv;
          if constexpr (ACT == 1) v = (v > 0.f) ? (v + 1.f) : __expf(v);
          Y[(size_t)(r0 + i) * NDIM + col] = (TOUT)v;
        }
      }
    }
  }

  // ---- CVT tail: convert next projection's input while other blocks
  // are still in their MFMA phases (dispatch-level overlap).
  if constexpr (CVT) {
    const int n8 = MROWS * KDIM / 8;   // 2,097,152
    for (int i = bid * 512 + tid; i < n8; i += 256 * 512) {
      float4 f0 = ((const float4*)csrc)[2 * i];
      float4 f1 = ((const float4*)csrc)[2 * i + 1];
      half8 h;
      h[0] = (_Float16)f0.x; h[1] = (_Float16)f0.y;
      h[2] = (_Float16)f0.z; h[3] = (_Float16)f0.w;
      h[4] = (_Float16)f1.x; h[5] = (_Float16)f1.y;
      h[6] = (_Float16)f1.z; h[7] = (_Float16)f1.w;
      ((half8*)cdst)[i] = h;
    }
  }
}

// ---------------------------------------------------------------------------
// kv_mfma: per (bh, chunk of 1024 l): partial C'[e][d] = sum_l VT[e][l]*KT[d][l]
// A = VT rows + synthesized ones-row (m-frag 4 -> Ksum); B = KT rows.
// ---------------------------------------------------------------------------
__global__ __launch_bounds__(256, 2)
void kv_mfma(const _Float16* __restrict__ KT, const _Float16* __restrict__ VT,
             _Float16* __restrict__ pKV) {
  const int bh = blockIdx.x;      // 0..63
  const int ch = blockIdx.y;      // 0..3
  const int tid  = threadIdx.x;
  const int lane = tid & 63;
  const int w    = tid >> 6;

  __shared__ _Float16 As[64 * 64];
  __shared__ _Float16 Bs[64 * 64];

  const int lr = lane >> 3;
  const int ls = (lane & 7) ^ lr;
  const size_t lbase = (size_t)ch * 1024 + ls * 8;
  const _Float16* gA = VT + (size_t)(bh * 64 + w * 16 + lr) * 4096 + lbase;
  const _Float16* gB = KT + (size_t)(bh * 64 + w * 16 + lr) * 4096 + lbase;
  _Float16* ldsA = As + (w * 16) * 64;
  _Float16* ldsB = Bs + (w * 16) * 64;

  half8 aones;
#pragma unroll
  for (int j = 0; j < 8; ++j) aones[j] = (lane & 15) == 0 ? (_Float16)1.0f : (_Float16)0.0f;

  f32x4 acc[5] = {};

  for (int k0 = 0; k0 < 1024; k0 += 64) {
    __syncthreads();
#pragma unroll
    for (int c = 0; c < 2; ++c) {
      GLD_LDS16(gA + k0 + (size_t)(c * 8) * 4096, ldsA + c * 8 * 64);
      GLD_LDS16(gB + k0 + (size_t)(c * 8) * 4096, ldsB + c * 8 * 64);
    }
    __syncthreads();

    half8 afr[4][2], bfr[2];
#pragma unroll
    for (int m = 0; m < 4; ++m)
#pragma unroll
      for (int kk = 0; kk < 2; ++kk) {
        int row  = m * 16 + (lane & 15);
        int byte = row * 128 + ((lane >> 4) << 4) + kk * 64;
        byte ^= (row & 7) << 4;
        afr[m][kk] = *(const half8*)((const char*)As + byte);
      }
#pragma unroll
    for (int kk = 0; kk < 2; ++kk) {
      int row  = w * 16 + (lane & 15);
      int byte = row * 128 + ((lane >> 4) << 4) + kk * 64;
      byte ^= (row & 7) << 4;
      bfr[kk] = *(const half8*)((const char*)Bs + byte);
    }
#pragma unroll
    for (int kk = 0; kk < 2; ++kk) {
#pragma unroll
      for (int m = 0; m < 4; ++m)
        acc[m] = __builtin_amdgcn_mfma_f32_16x16x32_f16(afr[m][kk], bfr[kk],
                                                        acc[m], 0, 0, 0);
      acc[4] = __builtin_amdgcn_mfma_f32_16x16x32_f16(aones, bfr[kk],
                                                      acc[4], 0, 0, 0);
    }
  }

  _Float16* outp = pKV + ((size_t)ch * 64 + bh) * 5120;
  const int col = w * 16 + (lane & 15);
#pragma unroll
  for (int m = 0; m < 5; ++m) {
#pragma unroll
    for (int i = 0; i < 4; ++i) {
      int row = m * 16 + ((lane >> 4) << 2) + i;
      outp[row * 64 + col] = (_Float16)acc[m][i];
    }
  }
}

// ---------------------------------------------------------------------------
__global__ __launch_bounds__(256)
void kv_combine(const _Float16* __restrict__ pKV, _Float16* __restrict__ KVTx) {
  int g = blockIdx.x * 256 + threadIdx.x;   // 0..327679
  int bh = g / 5120;
  int j  = g - bh * 5120;
  float s = 0.f;
#pragma unroll
  for (int ch = 0; ch < 4; ++ch)
    s += (float)pKV[((size_t)ch * 64 + bh) * 5120 + j];
  KVTx[(size_t)bh * 5120 + j] = (_Float16)s;
}

// ---------------------------------------------------------------------------
extern "C" void kernel_launch(void* const* d_in, const int* in_sizes, int n_in,
                              void* d_out, int out_size, void* d_ws, size_t ws_size,
                              hipStream_t stream) {
  const float* q  = (const float*)d_in[0];
  const float* k  = (const float*)d_in[1];
  const float* v  = (const float*)d_in[2];
  const float* wq = (const float*)d_in[3];
  const float* bq = (const float*)d_in[4];
  const float* wk = (const float*)d_in[5];
  const float* bk = (const float*)d_in[6];
  const float* wv = (const float*)d_in[7];
  const float* bv = (const float*)d_in[8];
  const float* wo = (const float*)d_in[9];
  const float* bo = (const float*)d_in[10];
  float* out = (float*)d_out;

  char* ws = (char*)d_ws;
  _Float16* Xk   = (_Float16*)(ws);                      // 0..32MB
  _Float16* KT   = (_Float16*)(ws + 33554432);           // 32..64MB
  _Float16* VT   = (_Float16*)(ws + 67108864);           // 64..96MB
  _Float16* pKV  = (_Float16*)(ws + 100663296);          // 2.62MB over whk/whv
  _Float16* whk  = (_Float16*)(ws + 100663296);          // 2MB (dies after K-gemm)
  _Float16* whv  = (_Float16*)(ws + 102760448);          // 2MB (dies after V-gemm)
  _Float16* whq  = (_Float16*)(ws + 104857600);          // 2MB
  _Float16* who  = (_Float16*)(ws + 106954752);          // 2MB (lives to the end)
  _Float16* KVTx = (_Float16*)(ws + 109051904);          // 655KB
  _Float16* att  = KT;                                   // reuse KT after KV built
  // d_out (64MB) as scratch until the final GEMM:
  _Float16* Xv   = (_Float16*)d_out;                     // 0..32MB of d_out
  _Float16* Xq   = (_Float16*)((char*)d_out + 33554432); // 32..64MB of d_out

  const int N8_BIG = MROWS * KDIM / 8;             // 2,097,152
  const int GBLK8  = (MROWS / 256) * (NDIM / 256); // 256 blocks

  // weights (fused small): 262,144 f4 -> (1024,4)
  cvt_w<<<dim3(1024, 4), 256, 0, stream>>>(wq, whq, wk, whk, wv, whv, wo, who);

  // k convert (standalone — nothing to overlap with)
  cvt_f32_to_f16<<<4096, 256, 0, stream>>>(k, Xk, N8_BIG);

  // K projection + fused v-convert tail (overlaps cvt with GEMM)
  gemm_8ph<1, 1, 1, _Float16><<<GBLK8, 512, 0, stream>>>(
      Xk, whk, bk, KT, nullptr, v, Xv);
  // V projection + fused q-convert tail
  gemm_8ph<0, 1, 1, _Float16><<<GBLK8, 512, 0, stream>>>(
      Xv, whv, bv, VT, nullptr, q, Xq);

  kv_mfma<<<dim3(64, 4), 256, 0, stream>>>(KT, VT, pKV);
  kv_combine<<<1280, 256, 0, stream>>>(pKV, KVTx);

  // Q projection + attention fused (8-phase + per-wave Ct epilogue)
  gemm_8ph<1, 2, 0, _Float16><<<GBLK8, 512, 0, stream>>>(
      Xq, whq, bq, att, KVTx, nullptr, nullptr);

  // output projection (8-phase, natural fp32) -> d_out (Xv/Xq dead)
  gemm_8ph<0, 0, 0, float><<<GBLK8, 512, 0, stream>>>(
      att, who, bo, out, nullptr, nullptr, nullptr);
}